// Round 11
// baseline (307.056 us; speedup 1.0000x reference)
//
#include <hip/hip_runtime.h>
#include <hip/hip_bf16.h>

#define B_ 2
#define S_ 2048
#define HID_ 2048
#define NH_ 16
#define HD_ 128
#define NKV_ 4
#define M_ (B_*S_)          // 4096
#define NQKV_ 3072          // 2048 Q + 512 K + 512 V
// 1/sqrt(128) * log2(e): QK^T scores land in log2 domain -> exp2f softmax
#define QSCALE2 0.12752464484148957f
#define DEFER_THR 11.5425f  // 8 * log2(e)
#define NSPLIT 4

typedef __bf16 bf16x8 __attribute__((ext_vector_type(8)));
typedef float f32x4 __attribute__((ext_vector_type(4)));
typedef float f32x16 __attribute__((ext_vector_type(16)));

typedef __attribute__((address_space(1))) const unsigned int gas_uint;
typedef __attribute__((address_space(3))) unsigned int las_uint;

__device__ __forceinline__ unsigned short f2bfu(float x) {
  __hip_bfloat16 h = __float2bfloat16(x);
  return __builtin_bit_cast(unsigned short, h);
}

__device__ __forceinline__ unsigned int pack2bf(float lo, float hi) {
  return (unsigned int)f2bfu(lo) | ((unsigned int)f2bfu(hi) << 16);
}

__device__ __forceinline__ float bflo(unsigned int u) {
  return __builtin_bit_cast(float, u << 16);
}
__device__ __forceinline__ float bfhi(unsigned int u) {
  return __builtin_bit_cast(float, u & 0xffff0000u);
}
__device__ __forceinline__ float bf2f(unsigned short u) {
  return __builtin_bit_cast(float, (unsigned int)u << 16);
}

__device__ __forceinline__ void gload_lds16(const void* g, void* l) {
  __builtin_amdgcn_global_load_lds((gas_uint*)g, (las_uint*)l, 16, 0, 0);
}

// ---------------- prep kernels ----------------

__global__ void k_cvt(const float* __restrict__ src, unsigned short* __restrict__ dst, int n4) {
  int i = blockIdx.x * 256 + threadIdx.x;
  if (i >= n4) return;
  float4 v = ((const float4*)src)[i];
  ushort4 o;
  o.x = f2bfu(v.x); o.y = f2bfu(v.y); o.z = f2bfu(v.z); o.w = f2bfu(v.w);
  ((ushort4*)dst)[i] = o;
}

// dst[C][R] = bf16(src[R][C])  -- 32x32 LDS tile transpose
__global__ void k_tcvt(const float* __restrict__ src, unsigned short* __restrict__ dst, int R, int C) {
  __shared__ float t[32][33];
  int bc = blockIdx.x * 32, br = blockIdx.y * 32;
  int tx = threadIdx.x & 31, ty = threadIdx.x >> 5;
  for (int i = ty; i < 32; i += 8)
    t[i][tx] = src[(size_t)(br + i) * C + bc + tx];
  __syncthreads();
  for (int i = ty; i < 32; i += 8)
    dst[(size_t)(bc + i) * R + br + tx] = f2bfu(t[tx][i]);
}

__global__ void k_bias(const float* __restrict__ bq, const float* __restrict__ bk,
                       const float* __restrict__ bv, float* __restrict__ out) {
  int i = blockIdx.x * 256 + threadIdx.x;  // 3072
  float v = (i < 2048) ? bq[i] : (i < 2560 ? bk[i - 2048] : bv[i - 2560]);
  out[i] = v;
}

__global__ void k_ropetab(float* __restrict__ cosT, float* __restrict__ sinT) {
  int idx = blockIdx.x * 256 + threadIdx.x;  // S*64
  int s = idx >> 6, i = idx & 63;
  float invf = expf(-(float)i * (9.210340371976184f / 64.f));  // 10000^(-i/64)
  float ang = (float)s * invf;
  cosT[idx] = cosf(ang);
  sinT[idx] = sinf(ang);
}

// RoPE Q: Cqkv(bf16)[M][3072] -> Qr[B][NH][S][HD] bf16, pre-scaled by log2(e)/sqrt(HD)
__global__ void k_ropeq(const unsigned short* __restrict__ Cq, const float* __restrict__ cosT,
                        const float* __restrict__ sinT, unsigned short* __restrict__ Qr) {
  int idx = blockIdx.x * 256 + threadIdx.x;    // M*NH*64
  int i = idx & 63, h = (idx >> 6) & (NH_ - 1), m = idx >> 10;
  int s = m & (S_ - 1), b = m >> 11;
  const unsigned short* row = Cq + (size_t)m * NQKV_ + h * HD_;
  float x1 = bf2f(row[i]), x2 = bf2f(row[i + 64]);
  float c = cosT[(s << 6) + i], sn = sinT[(s << 6) + i];
  size_t base = ((size_t)(b * NH_ + h) * S_ + s) * HD_;
  Qr[base + i]      = f2bfu((x1 * c - x2 * sn) * QSCALE2);
  Qr[base + i + 64] = f2bfu((x1 * sn + x2 * c) * QSCALE2);
}

// RoPE K: -> Kr[B][NKV][S][HD] bf16 (no scale)
__global__ void k_ropek(const unsigned short* __restrict__ Cq, const float* __restrict__ cosT,
                        const float* __restrict__ sinT, unsigned short* __restrict__ Kr) {
  int idx = blockIdx.x * 256 + threadIdx.x;    // M*NKV*64
  int i = idx & 63, kv = (idx >> 6) & (NKV_ - 1), m = idx >> 8;
  int s = m & (S_ - 1), b = m >> 11;
  const unsigned short* row = Cq + (size_t)m * NQKV_ + 2048 + kv * HD_;
  float x1 = bf2f(row[i]), x2 = bf2f(row[i + 64]);
  float c = cosT[(s << 6) + i], sn = sinT[(s << 6) + i];
  size_t base = ((size_t)(b * NKV_ + kv) * S_ + s) * HD_;
  Kr[base + i]      = f2bfu(x1 * c - x2 * sn);
  Kr[base + i + 64] = f2bfu(x1 * sn + x2 * c);
}

// V: Cqkv(bf16)[...][2560+kv*128+d] -> Vt[B][NKV][HD][S] bf16 (transposed via LDS)
__global__ void k_vt(const unsigned short* __restrict__ Cq, unsigned short* __restrict__ Vt) {
  __shared__ unsigned short t[32][136];
  int bx = blockIdx.x;                 // B*NKV*(S/32) = 512
  int st = bx & 63, kv = (bx >> 6) & 3, b = bx >> 8;
  int s0 = st * 32;
  int tid = threadIdx.x;
  for (int j = 0; j < 16; ++j) {
    int idx = j * 256 + tid;           // 4096 = 32*128
    int si = idx >> 7, d = idx & 127;
    t[si][d] = Cq[(size_t)(b * S_ + s0 + si) * NQKV_ + 2560 + kv * HD_ + d];
  }
  __syncthreads();
  for (int j = 0; j < 16; ++j) {
    int idx = j * 256 + tid;
    int d = idx >> 5, si = idx & 31;
    Vt[((size_t)(b * NKV_ + kv) * HD_ + d) * S_ + s0 + si] = t[si][d];
  }
}

// ---------------- GEMM: C[M][N] = A[M][K] @ Bt[N][K]^T + bias ----------------
// m97 structure: 128x128 tile, BK=64, global_load_lds w=16, XOR-swizzled LDS (T2, rule #21)
// BF16OUT: write bf16 (for Cqkv, halves downstream traffic); else f32.

template <bool BF16OUT>
__global__ __launch_bounds__(256, 2)
void k_gemm(const unsigned short* __restrict__ A, const unsigned short* __restrict__ Bt,
            const float* __restrict__ bias, void* __restrict__ Cv,
            int Md, int Nd, int Kd) {
  __shared__ __align__(16) unsigned short As[128 * 64];
  __shared__ __align__(16) unsigned short Bs[128 * 64];
  int nt = Nd >> 7;
  int nwg = (Md >> 7) * nt;
  int bid = blockIdx.x;
  int wg = bid;
  if ((nwg & 7) == 0) { int cpx = nwg >> 3; wg = (bid & 7) * cpx + (bid >> 3); }
  int bm = wg / nt, bn = wg - bm * nt;
  int tid = threadIdx.x;
  int lane = tid & 63, w = tid >> 6;
  int wm = (w >> 1) << 6, wn = (w & 1) << 6;
  int lr = lane & 15, lg = lane >> 4;
  f32x4 acc[4][4] = {};

  const int chunkbase = w << 2;
  const int boff = lane << 4;
  const int nK = Kd >> 6;
  const size_t rowstride = (size_t)Kd * 2;  // bytes per row

  for (int kt = 0; kt < nK; ++kt) {
#pragma unroll
    for (int i = 0; i < 4; ++i) {
      int off = ((chunkbase + i) << 10) + boff;  // linear byte offset in 16KB tile
      int row = off >> 7;
      int colb = off & 127;
      int scolb = colb ^ ((row & 7) << 4);       // pre-swizzled global source (rule #21)
      const char* ga = (const char*)A + (size_t)(bm * 128 + row) * rowstride + (kt << 7) + scolb;
      const char* gb = (const char*)Bt + (size_t)(bn * 128 + row) * rowstride + (kt << 7) + scolb;
      gload_lds16(ga, (char*)As + ((chunkbase + i) << 10));
      gload_lds16(gb, (char*)Bs + ((chunkbase + i) << 10));
    }
    __syncthreads();
#pragma unroll
    for (int kk = 0; kk < 2; ++kk) {
      bf16x8 a[4], b[4];
      int kb = ((kk << 5) + (lg << 3)) << 1;
#pragma unroll
      for (int mi = 0; mi < 4; ++mi) {
        int row = wm + (mi << 4) + lr;
        a[mi] = *(const bf16x8*)((const char*)As + (row << 7) + (kb ^ ((row & 7) << 4)));
      }
#pragma unroll
      for (int ni = 0; ni < 4; ++ni) {
        int row = wn + (ni << 4) + lr;
        b[ni] = *(const bf16x8*)((const char*)Bs + (row << 7) + (kb ^ ((row & 7) << 4)));
      }
#pragma unroll
      for (int mi = 0; mi < 4; ++mi)
#pragma unroll
        for (int ni = 0; ni < 4; ++ni)
          acc[mi][ni] = __builtin_amdgcn_mfma_f32_16x16x32_bf16(a[mi], b[ni], acc[mi][ni], 0, 0, 0);
    }
    __syncthreads();
  }
  // C/D layout: col = lane&15, row = (lane>>4)*4 + reg (m89-verified)
#pragma unroll
  for (int mi = 0; mi < 4; ++mi) {
    int r0 = bm * 128 + wm + (mi << 4) + (lg << 2);
#pragma unroll
    for (int ni = 0; ni < 4; ++ni) {
      int col = bn * 128 + wn + (ni << 4) + lr;
      float bz = bias[col];
#pragma unroll
      for (int r = 0; r < 4; ++r) {
        float v = acc[mi][ni][r] + bz;
        if constexpr (BF16OUT)
          ((unsigned short*)Cv)[(size_t)(r0 + r) * Nd + col] = f2bfu(v);
        else
          ((float*)Cv)[(size_t)(r0 + r) * Nd + col] = v;
      }
    }
  }
}

// ---------------- flash attention v10: barrier-free 1-warp blocks x 4-way split-KV ----------------
// v9 structure with __launch_bounds__(64, 2): 256-reg unified VGPR+AGPR budget -> no spills
// (the (64,4)=128-reg cap forced the 64-AGPR accumulator into scratch; suspected cause of
// R10's graph-replay divergence + 489us cold launch). 64-thread blocks, 32 q-rows, KV32
// tiles strided by 128 (4 splits). No LDS, no barriers. Grid = 8192 waves; K/V from L2.

__global__ __launch_bounds__(64, 2)
void k_attn(const unsigned short* __restrict__ Qr, const unsigned short* __restrict__ Kr,
            const unsigned short* __restrict__ Vt,
            unsigned short* __restrict__ Po0, unsigned short* __restrict__ Po1,
            unsigned short* __restrict__ Po2, unsigned short* __restrict__ Po3,
            float2* __restrict__ Ml) {
  int bid = blockIdx.x;
  int g = bid & 7;                 // (b,kvh) group -> XCD via round-robin dispatch
  int b = g >> 2, kvh = g & 3;
  int r = bid >> 3;                // 0..1023
  int split = r & 3;
  int r2 = r >> 2;                 // 0..255
  int hg = r2 >> 6;                // q-head within group 0..3
  int qw = 63 - (r2 & 63);         // q-warp 0..63, long blocks first
  int h = (kvh << 2) + hg;
  int lane = threadIdx.x & 63;
  int ql = lane & 31, hi = lane >> 5;
  int q0 = qw << 5;
  int qrow = q0 + ql;              // this lane's q row

  const unsigned short* Qp = Qr + (((size_t)(b * NH_ + h) * S_) << 7);
  const unsigned short* Kp = Kr + (((size_t)(b * NKV_ + kvh) * S_) << 7);
  const unsigned short* Vp = Vt + (((size_t)(b * NKV_ + kvh) * HD_) << 11);

  // Q fragments: qa[c] = Q[qrow][c*16 + hi*8 .. +8]  (B-operand of swapped QK^T)
  bf16x8 qa[8];
#pragma unroll
  for (int c = 0; c < 8; ++c)
    qa[c] = *(const bf16x8*)(Qp + (((size_t)qrow) << 7) + (c << 4) + (hi << 3));

  f32x16 acc[4] = {};              // acc[dc][r] = O^T[d = dc*32 + crow(r,hi)][qrow]
  float m_r = -1e30f, l_r = 0.f;   // l_r = partial (this half's 16 kv); combined at epilogue

  const int kv0 = split << 5;      // this split's tiles: kv0, kv0+128, kv0+256, ...

  // prologue: first K tile into registers
  bf16x8 kc[8];
  if (kv0 <= q0) {
    const unsigned short* kp0 = Kp + ((size_t)(kv0 + ql) << 7) + (hi << 3);
#pragma unroll
    for (int c = 0; c < 8; ++c) kc[c] = *(const bf16x8*)(kp0 + (c << 4));
  }

  for (int kvbase = kv0; kvbase <= q0; kvbase += 128) {
    // V for current tile — issue early (hidden under QK+softmax)
    bf16x8 vf[8];
#pragma unroll
    for (int dc = 0; dc < 4; ++dc) {
      const unsigned short* vrow = Vp + (((size_t)((dc << 5) + ql)) << 11) + kvbase + (hi << 3);
      vf[2 * dc]     = *(const bf16x8*)(vrow);
      vf[2 * dc + 1] = *(const bf16x8*)(vrow + 16);
    }
    // QK^T: two independent 4-chains
    f32x16 stl = {}, sth = {};
#pragma unroll
    for (int c = 0; c < 4; ++c) {
      stl = __builtin_amdgcn_mfma_f32_32x32x16_bf16(kc[c], qa[c], stl, 0, 0, 0);
      sth = __builtin_amdgcn_mfma_f32_32x32x16_bf16(kc[c + 4], qa[c + 4], sth, 0, 0, 0);
    }
    // prefetch next K tile of this split (L2 latency hidden under softmax+PV)
    bf16x8 kn[8];
    {
      int nb = (kvbase + 128 <= q0) ? kvbase + 128 : kvbase;
      const unsigned short* knp = Kp + ((size_t)(nb + ql) << 7) + (hi << 3);
#pragma unroll
      for (int c = 0; c < 8; ++c) kn[c] = *(const bf16x8*)(knp + (c << 4));
    }
    f32x16 st = stl + sth;
    // causal mask, diagonal tile only: kv = kvbase + (r&3) + 8*(r>>2) + 4*hi
    if (kvbase == q0) {
#pragma unroll
      for (int rr = 0; rr < 16; ++rr) {
        int kv = kvbase + (rr & 3) + ((rr >> 2) << 3) + (hi << 2);
        if (kv > qrow) st[rr] = -1e30f;
      }
    }
    // lane-local online softmax in log2 domain (partner lane^32 has other 16 kv)
    float pmax = st[0];
#pragma unroll
    for (int rr = 1; rr < 16; ++rr) pmax = fmaxf(pmax, st[rr]);
    pmax = fmaxf(pmax, __shfl_xor(pmax, 32));
    if (!__all(pmax <= m_r + DEFER_THR)) {    // defer-max (T13)
      float mn = fmaxf(m_r, pmax);
      float al = exp2f(m_r - mn);
      m_r = mn;
      l_r *= al;
#pragma unroll
      for (int dc = 0; dc < 4; ++dc) acc[dc] = acc[dc] * al;
    }
    float p[16];
    float ps = 0.f;
#pragma unroll
    for (int rr = 0; rr < 16; ++rr) { p[rr] = exp2f(st[rr] - m_r); ps += p[rr]; }
    l_r += ps;                                // partial; combined at epilogue
    // pack P -> bf16 words; exchange only the 4 partner words each lane uses.
    unsigned int W[8];
#pragma unroll
    for (int i2 = 0; i2 < 8; ++i2) W[i2] = pack2bf(p[2 * i2], p[2 * i2 + 1]);
    unsigned int e0 = __shfl_xor(hi ? W[0] : W[2], 32);
    unsigned int e1 = __shfl_xor(hi ? W[1] : W[3], 32);
    unsigned int e2 = __shfl_xor(hi ? W[4] : W[6], 32);
    unsigned int e3 = __shfl_xor(hi ? W[5] : W[7], 32);
    uint4 u0, u1;
    u0.x = hi ? e0 : W[0];
    u0.y = hi ? e1 : W[1];
    u0.z = hi ? W[2] : e0;
    u0.w = hi ? W[3] : e1;
    u1.x = hi ? e2 : W[4];
    u1.y = hi ? e3 : W[5];
    u1.z = hi ? W[6] : e2;
    u1.w = hi ? W[7] : e3;
    bf16x8 pa0 = __builtin_bit_cast(bf16x8, u0);
    bf16x8 pa1 = __builtin_bit_cast(bf16x8, u1);
    // PV: O^T += V^T · P^T ; A = V^T rows (d = dc*32 + ql)
#pragma unroll
    for (int dc = 0; dc < 4; ++dc) {
      acc[dc] = __builtin_amdgcn_mfma_f32_32x32x16_bf16(vf[2 * dc], pa0, acc[dc], 0, 0, 0);
      acc[dc] = __builtin_amdgcn_mfma_f32_32x32x16_bf16(vf[2 * dc + 1], pa1, acc[dc], 0, 0, 0);
    }
    // rotate prefetched K into place
#pragma unroll
    for (int c = 0; c < 8; ++c) kc[c] = kn[c];
  }

  // epilogue: combine half-row l partials; write normalized partial O + (m,l).
  float l_tot = l_r + __shfl_xor(l_r, 32);
  unsigned short* Pob = (split == 0) ? Po0 : (split == 1) ? Po1 : (split == 2) ? Po2 : Po3;
  float inv = (l_tot > 0.f) ? (1.f / l_tot) : 0.f;
  unsigned short* obase = Pob + ((((size_t)(b * S_) + qrow)) << 11) + (h << 7) + (hi << 2);
#pragma unroll
  for (int dc = 0; dc < 4; ++dc)
#pragma unroll
    for (int gq = 0; gq < 4; ++gq) {
      ushort4 o;
      o.x = f2bfu(acc[dc][4 * gq + 0] * inv);
      o.y = f2bfu(acc[dc][4 * gq + 1] * inv);
      o.z = f2bfu(acc[dc][4 * gq + 2] * inv);
      o.w = f2bfu(acc[dc][4 * gq + 3] * inv);
      *(ushort4*)(obase + (dc << 5) + (gq << 3)) = o;
    }
  if (hi == 0)
    Ml[(size_t)split * (M_ * NH_) + ((size_t)(b * S_) + qrow) * NH_ + h] = make_float2(m_r, l_tot);
}

// combine: Ob = sum_s w_s*Po_s / sum_s w_s, w_s = l_s * 2^(m_s - m)
__global__ void k_comb(const unsigned short* __restrict__ Po0, const unsigned short* __restrict__ Po1,
                       const unsigned short* __restrict__ Po2, const unsigned short* __restrict__ Po3,
                       const float2* __restrict__ Ml, unsigned short* __restrict__ Ob) {
  int idx = blockIdx.x * 256 + threadIdx.x;   // 1,048,576 threads, 8 elems each
  int c = idx >> 4;                           // 128-elem chunk = (b*S+s)*16 + h
  float2 a0 = Ml[c], a1 = Ml[c + M_ * NH_], a2 = Ml[c + 2 * M_ * NH_], a3 = Ml[c + 3 * M_ * NH_];
  float m = fmaxf(fmaxf(a0.x, a1.x), fmaxf(a2.x, a3.x));
  float w0 = a0.y * exp2f(a0.x - m);
  float w1 = a1.y * exp2f(a1.x - m);
  float w2 = a2.y * exp2f(a2.x - m);
  float w3 = a3.y * exp2f(a3.x - m);
  float inv = 1.f / (w0 + w1 + w2 + w3);
  w0 *= inv; w1 *= inv; w2 *= inv; w3 *= inv;
  size_t e = (size_t)idx << 3;
  uint4 v0 = *(const uint4*)(Po0 + e);
  uint4 v1 = *(const uint4*)(Po1 + e);
  uint4 v2 = *(const uint4*)(Po2 + e);
  uint4 v3 = *(const uint4*)(Po3 + e);
  uint4 o;
  o.x = pack2bf(w0 * bflo(v0.x) + w1 * bflo(v1.x) + w2 * bflo(v2.x) + w3 * bflo(v3.x),
                w0 * bfhi(v0.x) + w1 * bfhi(v1.x) + w2 * bfhi(v2.x) + w3 * bfhi(v3.x));
  o.y = pack2bf(w0 * bflo(v0.y) + w1 * bflo(v1.y) + w2 * bflo(v2.y) + w3 * bflo(v3.y),
                w0 * bfhi(v0.y) + w1 * bfhi(v1.y) + w2 * bfhi(v2.y) + w3 * bfhi(v3.y));
  o.z = pack2bf(w0 * bflo(v0.z) + w1 * bflo(v1.z) + w2 * bflo(v2.z) + w3 * bflo(v3.z),
                w0 * bfhi(v0.z) + w1 * bfhi(v1.z) + w2 * bfhi(v2.z) + w3 * bfhi(v3.z));
  o.w = pack2bf(w0 * bflo(v0.w) + w1 * bflo(v1.w) + w2 * bflo(v2.w) + w3 * bflo(v3.w),
                w0 * bfhi(v0.w) + w1 * bfhi(v1.w) + w2 * bfhi(v2.w) + w3 * bfhi(v3.w));
  *(uint4*)(Ob + e) = o;
}

// ---------------- launch ----------------

extern "C" void kernel_launch(void* const* d_in, const int* in_sizes, int n_in,
                              void* d_out, int out_size, void* d_ws, size_t ws_size,
                              hipStream_t stream) {
  const float* X  = (const float*)d_in[0];
  // d_in[1] = causal mask (structure known; ignored)
  const float* Wq = (const float*)d_in[2];
  const float* bq = (const float*)d_in[3];
  const float* Wk = (const float*)d_in[4];
  const float* bk = (const float*)d_in[5];
  const float* Wv = (const float*)d_in[6];
  const float* bv = (const float*)d_in[7];
  const float* Wo = (const float*)d_in[8];
  const float* bo = (const float*)d_in[9];
  float* out = (float*)d_out;

  char* ws = (char*)d_ws;
  unsigned short* Xb  = (unsigned short*)(ws);                  // 16,777,216 B
  unsigned short* Wt  = (unsigned short*)(ws + 16777216);       // 12,582,912
  unsigned short* Wot = (unsigned short*)(ws + 29360128);       //  8,388,608
  float* Bqkv         = (float*)(ws + 37748736);                //     12,288
  float* cosT         = (float*)(ws + 37761024);                //    524,288
  float* sinT         = (float*)(ws + 38285312);                //    524,288
  unsigned short* Cqkvb = (unsigned short*)(ws + 38809600);     // 25,165,824 (bf16 QKV)
  unsigned short* Qr  = (unsigned short*)(ws + 89141248);       // 16,777,216
  unsigned short* Kr  = (unsigned short*)(ws + 105918464);      //  4,194,304
  unsigned short* Vtb = (unsigned short*)(ws + 110112768);      //  4,194,304
  unsigned short* Ob  = (unsigned short*)(ws + 114307072);      // 16,777,216
  // split-KV partials overlaid on dead regions (after GEMM1 + rope/vt):
  unsigned short* Po0 = (unsigned short*)(ws);                            // Xb region, 16MB
  unsigned short* Po1 = (unsigned short*)(ws + 38809600);                 // Cqkv+0
  unsigned short* Po2 = (unsigned short*)(ws + 38809600 + 16777216);      // Cqkv+16M
  unsigned short* Po3 = (unsigned short*)(ws + 38809600 + 33554432);      // Cqkv+32M
  float2* Ml          = (float2*)(ws + 16777216);                         // Wt region, 2MB
  // total ~131 MB

  k_cvt<<<(M_ * HID_ / 4 + 255) / 256, 256, 0, stream>>>(X, Xb, M_ * HID_ / 4);
  k_tcvt<<<dim3(2048 / 32, 2048 / 32), 256, 0, stream>>>(Wq, Wt, 2048, 2048);
  k_tcvt<<<dim3(512 / 32, 2048 / 32), 256, 0, stream>>>(Wk, Wt + 2048 * 2048, 2048, 512);
  k_tcvt<<<dim3(512 / 32, 2048 / 32), 256, 0, stream>>>(Wv, Wt + 2560 * 2048, 2048, 512);
  k_tcvt<<<dim3(2048 / 32, 2048 / 32), 256, 0, stream>>>(Wo, Wot, 2048, 2048);
  k_bias<<<12, 256, 0, stream>>>(bq, bk, bv, Bqkv);
  k_ropetab<<<S_ * 64 / 256, 256, 0, stream>>>(cosT, sinT);

  k_gemm<true><<<(M_ / 128) * (NQKV_ / 128), 256, 0, stream>>>(Xb, Wt, Bqkv, Cqkvb, M_, NQKV_, HID_);

  k_ropeq<<<M_ * NH_ * 64 / 256, 256, 0, stream>>>(Cqkvb, cosT, sinT, Qr);
  k_ropek<<<M_ * NKV_ * 64 / 256, 256, 0, stream>>>(Cqkvb, cosT, sinT, Kr);
  k_vt<<<B_ * NKV_ * (S_ / 32), 256, 0, stream>>>(Cqkvb, Vtb);

  k_attn<<<B_ * NH_ * (S_ / 32) * NSPLIT, 64, 0, stream>>>(Qr, Kr, Vtb, Po0, Po1, Po2, Po3, Ml);
  k_comb<<<M_ * HID_ / 8 / 256, 256, 0, stream>>>(Po0, Po1, Po2, Po3, Ml, Ob);

  k_gemm<false><<<(M_ / 128) * (HID_ / 128), 256, 0, stream>>>(Ob, Wot, bo, out, M_, HID_, NH_ * HD_);
}

// Round 12
// 301.191 us; speedup vs baseline: 1.0195x; 1.0195x over previous
//
#include <hip/hip_runtime.h>
#include <hip/hip_bf16.h>

#define B_ 2
#define S_ 2048
#define HID_ 2048
#define NH_ 16
#define HD_ 128
#define NKV_ 4
#define M_ (B_*S_)          // 4096
#define NQKV_ 3072          // 2048 Q + 512 K + 512 V
// 1/sqrt(128) * log2(e): QK^T scores land in log2 domain -> exp2f softmax
#define QSCALE2 0.12752464484148957f
#define DEFER_THR 11.5425f  // 8 * log2(e)
#define NSPLIT 4

typedef __bf16 bf16x8 __attribute__((ext_vector_type(8)));
typedef float f32x4 __attribute__((ext_vector_type(4)));
typedef float f32x16 __attribute__((ext_vector_type(16)));

typedef __attribute__((address_space(1))) const unsigned int gas_uint;
typedef __attribute__((address_space(3))) unsigned int las_uint;

__device__ __forceinline__ unsigned short f2bfu(float x) {
  __hip_bfloat16 h = __float2bfloat16(x);
  return __builtin_bit_cast(unsigned short, h);
}

__device__ __forceinline__ unsigned int pack2bf(float lo, float hi) {
  return (unsigned int)f2bfu(lo) | ((unsigned int)f2bfu(hi) << 16);
}

__device__ __forceinline__ float bflo(unsigned int u) {
  return __builtin_bit_cast(float, u << 16);
}
__device__ __forceinline__ float bfhi(unsigned int u) {
  return __builtin_bit_cast(float, u & 0xffff0000u);
}
__device__ __forceinline__ float bf2f(unsigned short u) {
  return __builtin_bit_cast(float, (unsigned int)u << 16);
}

__device__ __forceinline__ void gload_lds16(const void* g, void* l) {
  __builtin_amdgcn_global_load_lds((gas_uint*)g, (las_uint*)l, 16, 0, 0);
}

// ---------------- prep kernels ----------------

__global__ void k_cvt(const float* __restrict__ src, unsigned short* __restrict__ dst, int n4) {
  int i = blockIdx.x * 256 + threadIdx.x;
  if (i >= n4) return;
  float4 v = ((const float4*)src)[i];
  ushort4 o;
  o.x = f2bfu(v.x); o.y = f2bfu(v.y); o.z = f2bfu(v.z); o.w = f2bfu(v.w);
  ((ushort4*)dst)[i] = o;
}

// dst[C][R] = bf16(src[R][C])  -- 32x32 LDS tile transpose
__global__ void k_tcvt(const float* __restrict__ src, unsigned short* __restrict__ dst, int R, int C) {
  __shared__ float t[32][33];
  int bc = blockIdx.x * 32, br = blockIdx.y * 32;
  int tx = threadIdx.x & 31, ty = threadIdx.x >> 5;
  for (int i = ty; i < 32; i += 8)
    t[i][tx] = src[(size_t)(br + i) * C + bc + tx];
  __syncthreads();
  for (int i = ty; i < 32; i += 8)
    dst[(size_t)(bc + i) * R + br + tx] = f2bfu(t[tx][i]);
}

__global__ void k_bias(const float* __restrict__ bq, const float* __restrict__ bk,
                       const float* __restrict__ bv, float* __restrict__ out) {
  int i = blockIdx.x * 256 + threadIdx.x;  // 3072
  float v = (i < 2048) ? bq[i] : (i < 2560 ? bk[i - 2048] : bv[i - 2560]);
  out[i] = v;
}

__global__ void k_ropetab(float* __restrict__ cosT, float* __restrict__ sinT) {
  int idx = blockIdx.x * 256 + threadIdx.x;  // S*64
  int s = idx >> 6, i = idx & 63;
  float invf = expf(-(float)i * (9.210340371976184f / 64.f));  // 10000^(-i/64)
  float ang = (float)s * invf;
  cosT[idx] = cosf(ang);
  sinT[idx] = sinf(ang);
}

// RoPE Q: Cqkv(bf16)[M][3072] -> Qr[B][NH][S][HD] bf16, pre-scaled by log2(e)/sqrt(HD)
__global__ void k_ropeq(const unsigned short* __restrict__ Cq, const float* __restrict__ cosT,
                        const float* __restrict__ sinT, unsigned short* __restrict__ Qr) {
  int idx = blockIdx.x * 256 + threadIdx.x;    // M*NH*64
  int i = idx & 63, h = (idx >> 6) & (NH_ - 1), m = idx >> 10;
  int s = m & (S_ - 1), b = m >> 11;
  const unsigned short* row = Cq + (size_t)m * NQKV_ + h * HD_;
  float x1 = bf2f(row[i]), x2 = bf2f(row[i + 64]);
  float c = cosT[(s << 6) + i], sn = sinT[(s << 6) + i];
  size_t base = ((size_t)(b * NH_ + h) * S_ + s) * HD_;
  Qr[base + i]      = f2bfu((x1 * c - x2 * sn) * QSCALE2);
  Qr[base + i + 64] = f2bfu((x1 * sn + x2 * c) * QSCALE2);
}

// RoPE K: -> Kr[B][NKV][S][HD] bf16 (no scale)
__global__ void k_ropek(const unsigned short* __restrict__ Cq, const float* __restrict__ cosT,
                        const float* __restrict__ sinT, unsigned short* __restrict__ Kr) {
  int idx = blockIdx.x * 256 + threadIdx.x;    // M*NKV*64
  int i = idx & 63, kv = (idx >> 6) & (NKV_ - 1), m = idx >> 8;
  int s = m & (S_ - 1), b = m >> 11;
  const unsigned short* row = Cq + (size_t)m * NQKV_ + 2048 + kv * HD_;
  float x1 = bf2f(row[i]), x2 = bf2f(row[i + 64]);
  float c = cosT[(s << 6) + i], sn = sinT[(s << 6) + i];
  size_t base = ((size_t)(b * NKV_ + kv) * S_ + s) * HD_;
  Kr[base + i]      = f2bfu(x1 * c - x2 * sn);
  Kr[base + i + 64] = f2bfu(x1 * sn + x2 * c);
}

// V: Cqkv(bf16)[...][2560+kv*128+d] -> Vt[B][NKV][HD][S] bf16 (transposed via LDS)
__global__ void k_vt(const unsigned short* __restrict__ Cq, unsigned short* __restrict__ Vt) {
  __shared__ unsigned short t[32][136];
  int bx = blockIdx.x;                 // B*NKV*(S/32) = 512
  int st = bx & 63, kv = (bx >> 6) & 3, b = bx >> 8;
  int s0 = st * 32;
  int tid = threadIdx.x;
  for (int j = 0; j < 16; ++j) {
    int idx = j * 256 + tid;           // 4096 = 32*128
    int si = idx >> 7, d = idx & 127;
    t[si][d] = Cq[(size_t)(b * S_ + s0 + si) * NQKV_ + 2560 + kv * HD_ + d];
  }
  __syncthreads();
  for (int j = 0; j < 16; ++j) {
    int idx = j * 256 + tid;
    int d = idx >> 5, si = idx & 31;
    Vt[((size_t)(b * NKV_ + kv) * HD_ + d) * S_ + s0 + si] = t[si][d];
  }
}

// ---------------- GEMM v2: counted-vmcnt pipelined, C[M][N] = A[M][K] @ Bt[N][K]^T + bias ----
// 128x128 tile, BK=32, 4 LDS buffers (64KB -> 2 blocks/CU), 3-tile-deep prefetch.
// Per phase: STAGE(t+3) -> swizzled ds_read_b128 -> setprio + 16 MFMA ->
// s_waitcnt vmcnt(8) (counted, never 0 in steady state) -> raw s_barrier (no drain).
// Swizzle (64B rows): colb ^= ((row>>1)&3)<<4, both-sides (rule #21); residual 2-way = free.
// Buffer discipline: phase t reads buf t&3; tiles t+1,t+2 landing (distinct bufs);
// stages (t+3)&3 (overwrites t-1's buf, safe: its reads completed before last barrier).

#define GSTAGE(bsel, t)                                                          \
  {                                                                              \
    size_t kb_ = (size_t)(t) << 6;                                               \
    _Pragma("unroll")                                                            \
    for (int i_ = 0; i_ < 2; ++i_) {                                             \
      int off_ = (i_ << 12) + (tid << 4);                                        \
      int row_ = off_ >> 6;                                                      \
      int scol_ = (off_ & 63) ^ (((row_ >> 1) & 3) << 4);                        \
      gload_lds16((const char*)Arow + (size_t)row_ * rowstride + kb_ + scol_,    \
                  (char*)As[bsel] + off_);                                       \
      gload_lds16((const char*)Brow + (size_t)row_ * rowstride + kb_ + scol_,    \
                  (char*)Bs[bsel] + off_);                                       \
    }                                                                            \
  }

template <bool BF16OUT>
__global__ __launch_bounds__(256, 2)
void k_gemm(const unsigned short* __restrict__ A, const unsigned short* __restrict__ Bt,
            const float* __restrict__ bias, void* __restrict__ Cv,
            int Md, int Nd, int Kd) {
  __shared__ __align__(16) unsigned short As[4][128 * 32];
  __shared__ __align__(16) unsigned short Bs[4][128 * 32];
  int nt = Nd >> 7;
  int nwg = (Md >> 7) * nt;
  int bid = blockIdx.x;
  int wg = bid;
  if ((nwg & 7) == 0) { int cpx = nwg >> 3; wg = (bid & 7) * cpx + (bid >> 3); }
  int bm = wg / nt, bn = wg - bm * nt;
  int tid = threadIdx.x;
  int lane = tid & 63, w = tid >> 6;
  int wm = (w >> 1) << 6, wn = (w & 1) << 6;
  int lr = lane & 15, lg = lane >> 4;
  f32x4 acc[4][4] = {};

  const size_t rowstride = (size_t)Kd * 2;  // bytes per row
  const int nKt = Kd >> 5;                  // 32-wide K tiles (64 for K=2048)
  const unsigned short* Arow = A + (size_t)(bm * 128) * Kd;
  const unsigned short* Brow = Bt + (size_t)(bn * 128) * Kd;

  // prologue: 3 tiles in flight; wait oldest (tile 0) landed
  GSTAGE(0, 0)
  GSTAGE(1, 1)
  GSTAGE(2, 2)
  asm volatile("s_waitcnt vmcnt(8)" ::: "memory");
  __builtin_amdgcn_sched_barrier(0);
  __builtin_amdgcn_s_barrier();

  for (int t = 0; t < nKt; ++t) {
    int bsel = t & 3;
    if (t + 3 < nKt) GSTAGE((t + 3) & 3, t + 3);
    bf16x8 a[4], b[4];
#pragma unroll
    for (int mi = 0; mi < 4; ++mi) {
      int row = wm + (mi << 4) + lr;
      a[mi] = *(const bf16x8*)((const char*)As[bsel] + (row << 6) +
                               ((lg << 4) ^ (((row >> 1) & 3) << 4)));
    }
#pragma unroll
    for (int ni = 0; ni < 4; ++ni) {
      int row = wn + (ni << 4) + lr;
      b[ni] = *(const bf16x8*)((const char*)Bs[bsel] + (row << 6) +
                               ((lg << 4) ^ (((row >> 1) & 3) << 4)));
    }
    __builtin_amdgcn_s_setprio(1);
#pragma unroll
    for (int mi = 0; mi < 4; ++mi)
#pragma unroll
      for (int ni = 0; ni < 4; ++ni)
        acc[mi][ni] = __builtin_amdgcn_mfma_f32_16x16x32_bf16(a[mi], b[ni], acc[mi][ni], 0, 0, 0);
    __builtin_amdgcn_s_setprio(0);
    // counted wait: land tile t+1 (oldest 4 outstanding loads), never drain in steady state
    if (t + 3 < nKt) {
      asm volatile("s_waitcnt vmcnt(8)" ::: "memory");
    } else if (t + 2 < nKt) {
      asm volatile("s_waitcnt vmcnt(4)" ::: "memory");
    } else if (t + 1 < nKt) {
      asm volatile("s_waitcnt vmcnt(0)" ::: "memory");
    }
    __builtin_amdgcn_sched_barrier(0);
    __builtin_amdgcn_s_barrier();
  }

  // C/D layout: col = lane&15, row = (lane>>4)*4 + reg (m89-verified)
#pragma unroll
  for (int mi = 0; mi < 4; ++mi) {
    int r0 = bm * 128 + wm + (mi << 4) + (lg << 2);
#pragma unroll
    for (int ni = 0; ni < 4; ++ni) {
      int col = bn * 128 + wn + (ni << 4) + lr;
      float bz = bias[col];
#pragma unroll
      for (int r = 0; r < 4; ++r) {
        float v = acc[mi][ni][r] + bz;
        if constexpr (BF16OUT)
          ((unsigned short*)Cv)[(size_t)(r0 + r) * Nd + col] = f2bfu(v);
        else
          ((float*)Cv)[(size_t)(r0 + r) * Nd + col] = v;
      }
    }
  }
}

// ---------------- flash attention v8 (REVERT to R9's proven 115us kernel) ----------------
// 4 warps x 32 q-rows, 4-way split-KV, KV64 double-buffered swizzled K LDS,
// swapped-operand 32x32 MFMA, lane-local exp2 softmax, partial-l, 4-shuffle exchange.

__global__ __launch_bounds__(256, 2)
void k_attn(const unsigned short* __restrict__ Qr, const unsigned short* __restrict__ Kr,
            const unsigned short* __restrict__ Vt,
            unsigned short* __restrict__ Po0, unsigned short* __restrict__ Po1,
            unsigned short* __restrict__ Po2, unsigned short* __restrict__ Po3,
            float2* __restrict__ Ml) {
  __shared__ __align__(16) unsigned short Ks[2][64 * 128];
  int bid = blockIdx.x;
  int g = bid & 7;                        // (b,kvh) group -> XCD via round-robin dispatch
  int b = g >> 2, kvh = g & 3;
  int r = bid >> 3;                       // 0..255
  int split = r & 3;
  int r2 = r >> 2;                        // 0..63
  int hg = r2 >> 4;                       // q-head within group 0..3
  int qt = 15 - (r2 & 15);                // long blocks first
  int h = (kvh << 2) + hg;
  int tid = threadIdx.x, lane = tid & 63, w = tid >> 6;
  int ql = lane & 31, hi = lane >> 5;
  int q0 = (qt << 7) + (w << 5);          // warp's first q row
  int qrow = q0 + ql;                     // this lane's q row

  const unsigned short* Qp = Qr + (((size_t)(b * NH_ + h) * S_) << 7);
  const unsigned short* Kp = Kr + (((size_t)(b * NKV_ + kvh) * S_) << 7);
  const unsigned short* Vp = Vt + (((size_t)(b * NKV_ + kvh) * HD_) << 11);

  // Q fragments: qa[c] = Q[qrow][c*16 + hi*8 .. +8]  (B-operand of swapped QK^T)
  bf16x8 qa[8];
#pragma unroll
  for (int c = 0; c < 8; ++c)
    qa[c] = *(const bf16x8*)(Qp + (((size_t)qrow) << 7) + (c << 4) + (hi << 3));

  f32x16 acc[4] = {};                     // acc[dc][r] = O^T[d = dc*32 + crow(r,hi)][qrow]
  float m_r = -1e30f, l_r = 0.f;          // l_r = partial (this half's 16 kv)

  const int T = (qt + 1) << 1;            // total KV64 tiles for this q-tile
  const int nit = (T - split + 3) >> 2;   // tiles for this split: t = split + 4*i

#define STAGE_K(bsel, t)                                                        \
  {                                                                             \
    const char* kbase = (const char*)Kp + ((size_t)(t) << 14);                  \
    _Pragma("unroll")                                                           \
    for (int i_ = 0; i_ < 4; ++i_) {                                            \
      int woff_ = (i_ << 12) + (w << 10);                                       \
      int off_ = woff_ + (lane << 4);                                           \
      int row_ = off_ >> 8;                                                     \
      int colb_ = off_ & 255;                                                   \
      int scolb_ = colb_ ^ ((row_ & 15) << 4);                                  \
      gload_lds16(kbase + ((size_t)row_ << 8) + scolb_,                         \
                  (char*)Ks[bsel] + woff_);                                     \
    }                                                                           \
  }

  STAGE_K(0, split);
  __syncthreads();

  for (int i = 0; i < nit; ++i) {
    int t = split + (i << 2);
    if (i + 1 < nit) STAGE_K((i + 1) & 1, t + 4);   // overlaps with compute below
    const char* Kb = (const char*)Ks[i & 1];

#pragma unroll
    for (int sub = 0; sub < 2; ++sub) {
      int kvbase = (t << 6) + (sub << 5);
      if (kvbase > q0 + 31) continue;     // fully masked for this warp (warp-uniform)

      // QK^T: S^T[kv][q], A = K rows (kv = sub*32 + ql), B = Q^T (from qa)
      f32x16 st = {};
      int krow = (sub << 5) + ql;
      int sw = (krow & 15) << 4;
#pragma unroll
      for (int c = 0; c < 8; ++c) {
        int cb = (c << 5) + (hi << 4);    // byte col within 256B row
        bf16x8 kf = *(const bf16x8*)(Kb + (krow << 8) + (cb ^ sw));
        st = __builtin_amdgcn_mfma_f32_32x32x16_bf16(kf, qa[c], st, 0, 0, 0);
      }
      // V loads issued early (VMEM latency hides under softmax)
      bf16x8 vf[8];
#pragma unroll
      for (int dc = 0; dc < 4; ++dc) {
        const unsigned short* vrow = Vp + (((size_t)((dc << 5) + ql)) << 11) + kvbase + (hi << 3);
        vf[2 * dc]     = *(const bf16x8*)(vrow);
        vf[2 * dc + 1] = *(const bf16x8*)(vrow + 16);
      }
      // causal mask on diagonal sub: kv = kvbase + (r&3) + 8*(r>>2) + 4*hi
      if (kvbase + 31 > q0) {
#pragma unroll
        for (int rr = 0; rr < 16; ++rr) {
          int kv = kvbase + (rr & 3) + ((rr >> 2) << 3) + (hi << 2);
          if (kv > qrow) st[rr] = -1e30f;
        }
      }
      // lane-local online softmax in log2 domain (partner lane^32 has other 16 kv)
      float pmax = st[0];
#pragma unroll
      for (int rr = 1; rr < 16; ++rr) pmax = fmaxf(pmax, st[rr]);
      pmax = fmaxf(pmax, __shfl_xor(pmax, 32));
      if (!__all(pmax <= m_r + DEFER_THR)) {    // defer-max (T13)
        float mn = fmaxf(m_r, pmax);
        float al = exp2f(m_r - mn);
        m_r = mn;
        l_r *= al;
#pragma unroll
        for (int dc = 0; dc < 4; ++dc) acc[dc] = acc[dc] * al;
      }
      float p[16];
      float ps = 0.f;
#pragma unroll
      for (int rr = 0; rr < 16; ++rr) { p[rr] = exp2f(st[rr] - m_r); ps += p[rr]; }
      l_r += ps;                                  // partial; combined at epilogue
      // pack P -> bf16 words; exchange only the 4 partner words each lane uses.
      unsigned int W[8];
#pragma unroll
      for (int i2 = 0; i2 < 8; ++i2) W[i2] = pack2bf(p[2 * i2], p[2 * i2 + 1]);
      unsigned int e0 = __shfl_xor(hi ? W[0] : W[2], 32);
      unsigned int e1 = __shfl_xor(hi ? W[1] : W[3], 32);
      unsigned int e2 = __shfl_xor(hi ? W[4] : W[6], 32);
      unsigned int e3 = __shfl_xor(hi ? W[5] : W[7], 32);
      uint4 u0, u1;
      u0.x = hi ? e0 : W[0];
      u0.y = hi ? e1 : W[1];
      u0.z = hi ? W[2] : e0;
      u0.w = hi ? W[3] : e1;
      u1.x = hi ? e2 : W[4];
      u1.y = hi ? e3 : W[5];
      u1.z = hi ? W[6] : e2;
      u1.w = hi ? W[7] : e3;
      bf16x8 pa0 = __builtin_bit_cast(bf16x8, u0);
      bf16x8 pa1 = __builtin_bit_cast(bf16x8, u1);
      // PV: O^T += V^T · P^T ; A = V^T rows (d = dc*32 + ql)
#pragma unroll
      for (int dc = 0; dc < 4; ++dc) {
        acc[dc] = __builtin_amdgcn_mfma_f32_32x32x16_bf16(vf[2 * dc], pa0, acc[dc], 0, 0, 0);
        acc[dc] = __builtin_amdgcn_mfma_f32_32x32x16_bf16(vf[2 * dc + 1], pa1, acc[dc], 0, 0, 0);
      }
    }
    __syncthreads();  // all waves done with Ks[i&1]; drains next-tile stage
  }

  // epilogue: combine the two half-row l partials; write normalized partial O + (m,l).
  float l_tot = l_r + __shfl_xor(l_r, 32);
  unsigned short* Pob = (split == 0) ? Po0 : (split == 1) ? Po1 : (split == 2) ? Po2 : Po3;
  float inv = (l_tot > 0.f) ? (1.f / l_tot) : 0.f;
  unsigned short* obase = Pob + ((((size_t)(b * S_) + qrow)) << 11) + (h << 7) + (hi << 2);
#pragma unroll
  for (int dc = 0; dc < 4; ++dc)
#pragma unroll
    for (int gq = 0; gq < 4; ++gq) {
      ushort4 o;
      o.x = f2bfu(acc[dc][4 * gq + 0] * inv);
      o.y = f2bfu(acc[dc][4 * gq + 1] * inv);
      o.z = f2bfu(acc[dc][4 * gq + 2] * inv);
      o.w = f2bfu(acc[dc][4 * gq + 3] * inv);
      *(ushort4*)(obase + (dc << 5) + (gq << 3)) = o;
    }
  if (hi == 0)
    Ml[(size_t)split * (M_ * NH_) + ((size_t)(b * S_) + qrow) * NH_ + h] = make_float2(m_r, l_tot);
}

// combine: Ob = sum_s w_s*Po_s / sum_s w_s, w_s = l_s * 2^(m_s - m)
__global__ void k_comb(const unsigned short* __restrict__ Po0, const unsigned short* __restrict__ Po1,
                       const unsigned short* __restrict__ Po2, const unsigned short* __restrict__ Po3,
                       const float2* __restrict__ Ml, unsigned short* __restrict__ Ob) {
  int idx = blockIdx.x * 256 + threadIdx.x;   // 1,048,576 threads, 8 elems each
  int c = idx >> 4;                           // 128-elem chunk = (b*S+s)*16 + h
  float2 a0 = Ml[c], a1 = Ml[c + M_ * NH_], a2 = Ml[c + 2 * M_ * NH_], a3 = Ml[c + 3 * M_ * NH_];
  float m = fmaxf(fmaxf(a0.x, a1.x), fmaxf(a2.x, a3.x));
  float w0 = a0.y * exp2f(a0.x - m);
  float w1 = a1.y * exp2f(a1.x - m);
  float w2 = a2.y * exp2f(a2.x - m);
  float w3 = a3.y * exp2f(a3.x - m);
  float inv = 1.f / (w0 + w1 + w2 + w3);
  w0 *= inv; w1 *= inv; w2 *= inv; w3 *= inv;
  size_t e = (size_t)idx << 3;
  uint4 v0 = *(const uint4*)(Po0 + e);
  uint4 v1 = *(const uint4*)(Po1 + e);
  uint4 v2 = *(const uint4*)(Po2 + e);
  uint4 v3 = *(const uint4*)(Po3 + e);
  uint4 o;
  o.x = pack2bf(w0 * bflo(v0.x) + w1 * bflo(v1.x) + w2 * bflo(v2.x) + w3 * bflo(v3.x),
                w0 * bfhi(v0.x) + w1 * bfhi(v1.x) + w2 * bfhi(v2.x) + w3 * bfhi(v3.x));
  o.y = pack2bf(w0 * bflo(v0.y) + w1 * bflo(v1.y) + w2 * bflo(v2.y) + w3 * bflo(v3.y),
                w0 * bfhi(v0.y) + w1 * bfhi(v1.y) + w2 * bfhi(v2.y) + w3 * bfhi(v3.y));
  o.z = pack2bf(w0 * bflo(v0.z) + w1 * bflo(v1.z) + w2 * bflo(v2.z) + w3 * bflo(v3.z),
                w0 * bfhi(v0.z) + w1 * bfhi(v1.z) + w2 * bfhi(v2.z) + w3 * bfhi(v3.z));
  o.w = pack2bf(w0 * bflo(v0.w) + w1 * bflo(v1.w) + w2 * bflo(v2.w) + w3 * bflo(v3.w),
                w0 * bfhi(v0.w) + w1 * bfhi(v1.w) + w2 * bfhi(v2.w) + w3 * bfhi(v3.w));
  *(uint4*)(Ob + e) = o;
}

// ---------------- launch ----------------

extern "C" void kernel_launch(void* const* d_in, const int* in_sizes, int n_in,
                              void* d_out, int out_size, void* d_ws, size_t ws_size,
                              hipStream_t stream) {
  const float* X  = (const float*)d_in[0];
  // d_in[1] = causal mask (structure known; ignored)
  const float* Wq = (const float*)d_in[2];
  const float* bq = (const float*)d_in[3];
  const float* Wk = (const float*)d_in[4];
  const float* bk = (const float*)d_in[5];
  const float* Wv = (const float*)d_in[6];
  const float* bv = (const float*)d_in[7];
  const float* Wo = (const float*)d_in[8];
  const float* bo = (const float*)d_in[9];
  float* out = (float*)d_out;

  char* ws = (char*)d_ws;
  unsigned short* Xb  = (unsigned short*)(ws);                  // 16,777,216 B
  unsigned short* Wt  = (unsigned short*)(ws + 16777216);       // 12,582,912
  unsigned short* Wot = (unsigned short*)(ws + 29360128);       //  8,388,608
  float* Bqkv         = (float*)(ws + 37748736);                //     12,288
  float* cosT         = (float*)(ws + 37761024);                //    524,288
  float* sinT         = (float*)(ws + 38285312);                //    524,288
  unsigned short* Cqkvb = (unsigned short*)(ws + 38809600);     // 25,165,824 (bf16 QKV)
  unsigned short* Qr  = (unsigned short*)(ws + 89141248);       // 16,777,216
  unsigned short* Kr  = (unsigned short*)(ws + 105918464);      //  4,194,304
  unsigned short* Vtb = (unsigned short*)(ws + 110112768);      //  4,194,304
  unsigned short* Ob  = (unsigned short*)(ws + 114307072);      // 16,777,216
  // split-KV partials overlaid on dead regions (after GEMM1 + rope/vt):
  unsigned short* Po0 = (unsigned short*)(ws);                            // Xb region, 16MB
  unsigned short* Po1 = (unsigned short*)(ws + 38809600);                 // Cqkv+0
  unsigned short* Po2 = (unsigned short*)(ws + 38809600 + 16777216);      // Cqkv+16M
  unsigned short* Po3 = (unsigned short*)(ws + 38809600 + 33554432);      // Cqkv+32M
  float2* Ml          = (float2*)(ws + 16777216);                         // Wt region, 2MB
  // total ~131 MB

  k_cvt<<<(M_ * HID_ / 4 + 255) / 256, 256, 0, stream>>>(X, Xb, M_ * HID_ / 4);
  k_tcvt<<<dim3(2048 / 32, 2048 / 32), 256, 0, stream>>>(Wq, Wt, 2048, 2048);
  k_tcvt<<<dim3(512 / 32, 2048 / 32), 256, 0, stream>>>(Wk, Wt + 2048 * 2048, 2048, 512);
  k_tcvt<<<dim3(512 / 32, 2048 / 32), 256, 0, stream>>>(Wv, Wt + 2560 * 2048, 2048, 512);
  k_tcvt<<<dim3(2048 / 32, 2048 / 32), 256, 0, stream>>>(Wo, Wot, 2048, 2048);
  k_bias<<<12, 256, 0, stream>>>(bq, bk, bv, Bqkv);
  k_ropetab<<<S_ * 64 / 256, 256, 0, stream>>>(cosT, sinT);

  k_gemm<true><<<(M_ / 128) * (NQKV_ / 128), 256, 0, stream>>>(Xb, Wt, Bqkv, Cqkvb, M_, NQKV_, HID_);

  k_ropeq<<<M_ * NH_ * 64 / 256, 256, 0, stream>>>(Cqkvb, cosT, sinT, Qr);
  k_ropek<<<M_ * NKV_ * 64 / 256, 256, 0, stream>>>(Cqkvb, cosT, sinT, Kr);
  k_vt<<<B_ * NKV_ * (S_ / 32), 256, 0, stream>>>(Cqkvb, Vtb);

  k_attn<<<B_ * NH_ * (S_ / 128) * NSPLIT, 256, 0, stream>>>(Qr, Kr, Vtb, Po0, Po1, Po2, Po3, Ml);
  k_comb<<<M_ * HID_ / 8 / 256, 256, 0, stream>>>(Po0, Po1, Po2, Po3, Ml, Ob);

  k_gemm<false><<<(M_ / 128) * (HID_ / 128), 256, 0, stream>>>(Ob, Wot, bo, out, M_, HID_, NH_ * HD_);
}

// Round 13
// 237.219 us; speedup vs baseline: 1.2944x; 1.2697x over previous
//
#include <hip/hip_runtime.h>
#include <hip/hip_bf16.h>

#define B_ 2
#define S_ 2048
#define HID_ 2048
#define NH_ 16
#define HD_ 128
#define NKV_ 4
#define M_ (B_*S_)          // 4096
#define NQKV_ 3072          // 2048 Q + 512 K + 512 V
// 1/sqrt(128) * log2(e): QK^T scores land in log2 domain -> exp2f softmax
#define QSCALE2 0.12752464484148957f
#define DEFER_THR 11.5425f  // 8 * log2(e)
#define NSPLIT 4

typedef __bf16 bf16x8 __attribute__((ext_vector_type(8)));
typedef float f32x4 __attribute__((ext_vector_type(4)));
typedef float f32x16 __attribute__((ext_vector_type(16)));

typedef __attribute__((address_space(1))) const unsigned int gas_uint;
typedef __attribute__((address_space(3))) unsigned int las_uint;

__device__ __forceinline__ unsigned short f2bfu(float x) {
  __hip_bfloat16 h = __float2bfloat16(x);
  return __builtin_bit_cast(unsigned short, h);
}

__device__ __forceinline__ unsigned int pack2bf(float lo, float hi) {
  return (unsigned int)f2bfu(lo) | ((unsigned int)f2bfu(hi) << 16);
}

__device__ __forceinline__ float bflo(unsigned int u) {
  return __builtin_bit_cast(float, u << 16);
}
__device__ __forceinline__ float bfhi(unsigned int u) {
  return __builtin_bit_cast(float, u & 0xffff0000u);
}
__device__ __forceinline__ float bf2f(unsigned short u) {
  return __builtin_bit_cast(float, (unsigned int)u << 16);
}

__device__ __forceinline__ void gload_lds16(const void* g, void* l) {
  __builtin_amdgcn_global_load_lds((gas_uint*)g, (las_uint*)l, 16, 0, 0);
}

// ---------------- merged prep kernels ----------------

// regions: [0,8192) X f32->bf16 cvt ; [8192,8204) bias concat ; [8204,8716) rope table
__global__ void k_prep(const float* __restrict__ X, unsigned short* __restrict__ Xb,
                       const float* __restrict__ bq, const float* __restrict__ bk,
                       const float* __restrict__ bv, float* __restrict__ Bqkv,
                       float* __restrict__ cosT, float* __restrict__ sinT) {
  int blk = blockIdx.x;
  if (blk < 8192) {
    int i = blk * 256 + threadIdx.x;           // 2,097,152 float4s
    float4 v = ((const float4*)X)[i];
    ushort4 o;
    o.x = f2bfu(v.x); o.y = f2bfu(v.y); o.z = f2bfu(v.z); o.w = f2bfu(v.w);
    ((ushort4*)Xb)[i] = o;
  } else if (blk < 8204) {
    int i = (blk - 8192) * 256 + threadIdx.x;  // 3072
    float v = (i < 2048) ? bq[i] : (i < 2560 ? bk[i - 2048] : bv[i - 2560]);
    Bqkv[i] = v;
  } else {
    int idx = (blk - 8204) * 256 + threadIdx.x;  // S*64
    int s = idx >> 6, i = idx & 63;
    float invf = expf(-(float)i * (9.210340371976184f / 64.f));  // 10000^(-i/64)
    float ang = (float)s * invf;
    cosT[idx] = cosf(ang);
    sinT[idx] = sinf(ang);
  }
}

// dst[C][R] = bf16(src[R][C]) -- 32x32 LDS transpose; flat tile decode over 4 weights
__global__ void k_tcvtall(const float* __restrict__ Wq, const float* __restrict__ Wk,
                          const float* __restrict__ Wv, const float* __restrict__ Wo,
                          unsigned short* __restrict__ Wt, unsigned short* __restrict__ Wot) {
  __shared__ float t[32][33];
  int blk = blockIdx.x;   // 10240 tiles
  const float* src;
  unsigned short* dst;
  int R, C, bx, by;
  if (blk < 4096)      { src = Wq; dst = Wt;              R = 2048; C = 2048; int i = blk;        bx = i & 63; by = i >> 6; }
  else if (blk < 5120) { src = Wk; dst = Wt + 2048*2048;  R = 2048; C = 512;  int i = blk - 4096; bx = i & 15; by = i >> 4; }
  else if (blk < 6144) { src = Wv; dst = Wt + 2560*2048;  R = 2048; C = 512;  int i = blk - 5120; bx = i & 15; by = i >> 4; }
  else                 { src = Wo; dst = Wot;             R = 2048; C = 2048; int i = blk - 6144; bx = i & 63; by = i >> 6; }
  int bc = bx * 32, br = by * 32;
  int tx = threadIdx.x & 31, ty = threadIdx.x >> 5;
  for (int i = ty; i < 32; i += 8)
    t[i][tx] = src[(size_t)(br + i) * C + bc + tx];
  __syncthreads();
  for (int i = ty; i < 32; i += 8)
    dst[(size_t)(bc + i) * R + br + tx] = f2bfu(t[tx][i]);
}

// merged RoPE-Q / RoPE-K / V-transpose (regions; branch is block-uniform)
// [0,16384): ropeq ; [16384,20480): ropek ; [20480,20992): vt
__global__ void k_rope(const unsigned short* __restrict__ Cq, const float* __restrict__ cosT,
                       const float* __restrict__ sinT, unsigned short* __restrict__ Qr,
                       unsigned short* __restrict__ Kr, unsigned short* __restrict__ Vt) {
  __shared__ unsigned short t[32][136];
  int blk = blockIdx.x;
  if (blk < 16384) {
    int idx = blk * 256 + threadIdx.x;    // M*NH*64
    int i = idx & 63, h = (idx >> 6) & (NH_ - 1), m = idx >> 10;
    int s = m & (S_ - 1), b = m >> 11;
    const unsigned short* row = Cq + (size_t)m * NQKV_ + h * HD_;
    float x1 = bf2f(row[i]), x2 = bf2f(row[i + 64]);
    float c = cosT[(s << 6) + i], sn = sinT[(s << 6) + i];
    size_t base = ((size_t)(b * NH_ + h) * S_ + s) * HD_;
    Qr[base + i]      = f2bfu((x1 * c - x2 * sn) * QSCALE2);
    Qr[base + i + 64] = f2bfu((x1 * sn + x2 * c) * QSCALE2);
  } else if (blk < 20480) {
    int idx = (blk - 16384) * 256 + threadIdx.x;    // M*NKV*64
    int i = idx & 63, kv = (idx >> 6) & (NKV_ - 1), m = idx >> 8;
    int s = m & (S_ - 1), b = m >> 11;
    const unsigned short* row = Cq + (size_t)m * NQKV_ + 2048 + kv * HD_;
    float x1 = bf2f(row[i]), x2 = bf2f(row[i + 64]);
    float c = cosT[(s << 6) + i], sn = sinT[(s << 6) + i];
    size_t base = ((size_t)(b * NKV_ + kv) * S_ + s) * HD_;
    Kr[base + i]      = f2bfu(x1 * c - x2 * sn);
    Kr[base + i + 64] = f2bfu(x1 * sn + x2 * c);
  } else {
    int bx = blk - 20480;                // 512
    int st = bx & 63, kv = (bx >> 6) & 3, b = bx >> 8;
    int s0 = st * 32;
    int tid = threadIdx.x;
    for (int j = 0; j < 16; ++j) {
      int idx = j * 256 + tid;           // 4096 = 32*128
      int si = idx >> 7, d = idx & 127;
      t[si][d] = Cq[(size_t)(b * S_ + s0 + si) * NQKV_ + 2560 + kv * HD_ + d];
    }
    __syncthreads();
    for (int j = 0; j < 16; ++j) {
      int idx = j * 256 + tid;
      int d = idx >> 5, si = idx & 31;
      Vt[((size_t)(b * NKV_ + kv) * HD_ + d) * S_ + s0 + si] = t[si][d];
    }
  }
}

// ---------------- GEMM: C[M][N] = A[M][K] @ Bt[N][K]^T + bias ----------------
// m97 structure (replay-proven R9): 128x128 tile, BK=64, global_load_lds w=16,
// XOR-swizzled LDS (T2, rule #21). BF16OUT: write bf16 (Cqkv); else f32.

template <bool BF16OUT>
__global__ __launch_bounds__(256, 2)
void k_gemm(const unsigned short* __restrict__ A, const unsigned short* __restrict__ Bt,
            const float* __restrict__ bias, void* __restrict__ Cv,
            int Md, int Nd, int Kd) {
  __shared__ __align__(16) unsigned short As[128 * 64];
  __shared__ __align__(16) unsigned short Bs[128 * 64];
  int nt = Nd >> 7;
  int nwg = (Md >> 7) * nt;
  int bid = blockIdx.x;
  int wg = bid;
  if ((nwg & 7) == 0) { int cpx = nwg >> 3; wg = (bid & 7) * cpx + (bid >> 3); }
  int bm = wg / nt, bn = wg - bm * nt;
  int tid = threadIdx.x;
  int lane = tid & 63, w = tid >> 6;
  int wm = (w >> 1) << 6, wn = (w & 1) << 6;
  int lr = lane & 15, lg = lane >> 4;
  f32x4 acc[4][4] = {};

  const int chunkbase = w << 2;
  const int boff = lane << 4;
  const int nK = Kd >> 6;
  const size_t rowstride = (size_t)Kd * 2;  // bytes per row

  for (int kt = 0; kt < nK; ++kt) {
#pragma unroll
    for (int i = 0; i < 4; ++i) {
      int off = ((chunkbase + i) << 10) + boff;  // linear byte offset in 16KB tile
      int row = off >> 7;
      int colb = off & 127;
      int scolb = colb ^ ((row & 7) << 4);       // pre-swizzled global source (rule #21)
      const char* ga = (const char*)A + (size_t)(bm * 128 + row) * rowstride + (kt << 7) + scolb;
      const char* gb = (const char*)Bt + (size_t)(bn * 128 + row) * rowstride + (kt << 7) + scolb;
      gload_lds16(ga, (char*)As + ((chunkbase + i) << 10));
      gload_lds16(gb, (char*)Bs + ((chunkbase + i) << 10));
    }
    __syncthreads();
#pragma unroll
    for (int kk = 0; kk < 2; ++kk) {
      bf16x8 a[4], b[4];
      int kb = ((kk << 5) + (lg << 3)) << 1;
#pragma unroll
      for (int mi = 0; mi < 4; ++mi) {
        int row = wm + (mi << 4) + lr;
        a[mi] = *(const bf16x8*)((const char*)As + (row << 7) + (kb ^ ((row & 7) << 4)));
      }
#pragma unroll
      for (int ni = 0; ni < 4; ++ni) {
        int row = wn + (ni << 4) + lr;
        b[ni] = *(const bf16x8*)((const char*)Bs + (row << 7) + (kb ^ ((row & 7) << 4)));
      }
#pragma unroll
      for (int mi = 0; mi < 4; ++mi)
#pragma unroll
        for (int ni = 0; ni < 4; ++ni)
          acc[mi][ni] = __builtin_amdgcn_mfma_f32_16x16x32_bf16(a[mi], b[ni], acc[mi][ni], 0, 0, 0);
    }
    __syncthreads();
  }
  // C/D layout: col = lane&15, row = (lane>>4)*4 + reg (m89-verified)
#pragma unroll
  for (int mi = 0; mi < 4; ++mi) {
    int r0 = bm * 128 + wm + (mi << 4) + (lg << 2);
#pragma unroll
    for (int ni = 0; ni < 4; ++ni) {
      int col = bn * 128 + wn + (ni << 4) + lr;
      float bz = bias[col];
#pragma unroll
      for (int r = 0; r < 4; ++r) {
        float v = acc[mi][ni][r] + bz;
        if constexpr (BF16OUT)
          ((unsigned short*)Cv)[(size_t)(r0 + r) * Nd + col] = f2bfu(v);
        else
          ((float*)Cv)[(size_t)(r0 + r) * Nd + col] = v;
      }
    }
  }
}

// ---------------- flash attention v8 (R9's proven 115us kernel, unchanged) ----------------
// 4 warps x 32 q-rows, 4-way split-KV, KV64 double-buffered swizzled K LDS,
// swapped-operand 32x32 MFMA, lane-local exp2 softmax, partial-l, 4-shuffle exchange.

__global__ __launch_bounds__(256, 2)
void k_attn(const unsigned short* __restrict__ Qr, const unsigned short* __restrict__ Kr,
            const unsigned short* __restrict__ Vt,
            unsigned short* __restrict__ Po0, unsigned short* __restrict__ Po1,
            unsigned short* __restrict__ Po2, unsigned short* __restrict__ Po3,
            float2* __restrict__ Ml) {
  __shared__ __align__(16) unsigned short Ks[2][64 * 128];
  int bid = blockIdx.x;
  int g = bid & 7;                        // (b,kvh) group -> XCD via round-robin dispatch
  int b = g >> 2, kvh = g & 3;
  int r = bid >> 3;                       // 0..255
  int split = r & 3;
  int r2 = r >> 2;                        // 0..63
  int hg = r2 >> 4;                       // q-head within group 0..3
  int qt = 15 - (r2 & 15);                // long blocks first
  int h = (kvh << 2) + hg;
  int tid = threadIdx.x, lane = tid & 63, w = tid >> 6;
  int ql = lane & 31, hi = lane >> 5;
  int q0 = (qt << 7) + (w << 5);          // warp's first q row
  int qrow = q0 + ql;                     // this lane's q row

  const unsigned short* Qp = Qr + (((size_t)(b * NH_ + h) * S_) << 7);
  const unsigned short* Kp = Kr + (((size_t)(b * NKV_ + kvh) * S_) << 7);
  const unsigned short* Vp = Vt + (((size_t)(b * NKV_ + kvh) * HD_) << 11);

  // Q fragments: qa[c] = Q[qrow][c*16 + hi*8 .. +8]  (B-operand of swapped QK^T)
  bf16x8 qa[8];
#pragma unroll
  for (int c = 0; c < 8; ++c)
    qa[c] = *(const bf16x8*)(Qp + (((size_t)qrow) << 7) + (c << 4) + (hi << 3));

  f32x16 acc[4] = {};                     // acc[dc][r] = O^T[d = dc*32 + crow(r,hi)][qrow]
  float m_r = -1e30f, l_r = 0.f;          // l_r = partial (this half's 16 kv)

  const int T = (qt + 1) << 1;            // total KV64 tiles for this q-tile
  const int nit = (T - split + 3) >> 2;   // tiles for this split: t = split + 4*i

#define STAGE_K(bsel, t)                                                        \
  {                                                                             \
    const char* kbase = (const char*)Kp + ((size_t)(t) << 14);                  \
    _Pragma("unroll")                                                           \
    for (int i_ = 0; i_ < 4; ++i_) {                                            \
      int woff_ = (i_ << 12) + (w << 10);                                       \
      int off_ = woff_ + (lane << 4);                                           \
      int row_ = off_ >> 8;                                                     \
      int colb_ = off_ & 255;                                                   \
      int scolb_ = colb_ ^ ((row_ & 15) << 4);                                  \
      gload_lds16(kbase + ((size_t)row_ << 8) + scolb_,                         \
                  (char*)Ks[bsel] + woff_);                                     \
    }                                                                           \
  }

  STAGE_K(0, split);
  __syncthreads();

  for (int i = 0; i < nit; ++i) {
    int t = split + (i << 2);
    if (i + 1 < nit) STAGE_K((i + 1) & 1, t + 4);   // overlaps with compute below
    const char* Kb = (const char*)Ks[i & 1];

#pragma unroll
    for (int sub = 0; sub < 2; ++sub) {
      int kvbase = (t << 6) + (sub << 5);
      if (kvbase > q0 + 31) continue;     // fully masked for this warp (warp-uniform)

      // QK^T: S^T[kv][q], A = K rows (kv = sub*32 + ql), B = Q^T (from qa)
      f32x16 st = {};
      int krow = (sub << 5) + ql;
      int sw = (krow & 15) << 4;
#pragma unroll
      for (int c = 0; c < 8; ++c) {
        int cb = (c << 5) + (hi << 4);    // byte col within 256B row
        bf16x8 kf = *(const bf16x8*)(Kb + (krow << 8) + (cb ^ sw));
        st = __builtin_amdgcn_mfma_f32_32x32x16_bf16(kf, qa[c], st, 0, 0, 0);
      }
      // V loads issued early (VMEM latency hides under softmax)
      bf16x8 vf[8];
#pragma unroll
      for (int dc = 0; dc < 4; ++dc) {
        const unsigned short* vrow = Vp + (((size_t)((dc << 5) + ql)) << 11) + kvbase + (hi << 3);
        vf[2 * dc]     = *(const bf16x8*)(vrow);
        vf[2 * dc + 1] = *(const bf16x8*)(vrow + 16);
      }
      // causal mask on diagonal sub: kv = kvbase + (r&3) + 8*(r>>2) + 4*hi
      if (kvbase + 31 > q0) {
#pragma unroll
        for (int rr = 0; rr < 16; ++rr) {
          int kv = kvbase + (rr & 3) + ((rr >> 2) << 3) + (hi << 2);
          if (kv > qrow) st[rr] = -1e30f;
        }
      }
      // lane-local online softmax in log2 domain (partner lane^32 has other 16 kv)
      float pmax = st[0];
#pragma unroll
      for (int rr = 1; rr < 16; ++rr) pmax = fmaxf(pmax, st[rr]);
      pmax = fmaxf(pmax, __shfl_xor(pmax, 32));
      if (!__all(pmax <= m_r + DEFER_THR)) {    // defer-max (T13)
        float mn = fmaxf(m_r, pmax);
        float al = exp2f(m_r - mn);
        m_r = mn;
        l_r *= al;
#pragma unroll
        for (int dc = 0; dc < 4; ++dc) acc[dc] = acc[dc] * al;
      }
      float p[16];
      float ps = 0.f;
#pragma unroll
      for (int rr = 0; rr < 16; ++rr) { p[rr] = exp2f(st[rr] - m_r); ps += p[rr]; }
      l_r += ps;                                  // partial; combined at epilogue
      // pack P -> bf16 words; exchange only the 4 partner words each lane uses.
      unsigned int W[8];
#pragma unroll
      for (int i2 = 0; i2 < 8; ++i2) W[i2] = pack2bf(p[2 * i2], p[2 * i2 + 1]);
      unsigned int e0 = __shfl_xor(hi ? W[0] : W[2], 32);
      unsigned int e1 = __shfl_xor(hi ? W[1] : W[3], 32);
      unsigned int e2 = __shfl_xor(hi ? W[4] : W[6], 32);
      unsigned int e3 = __shfl_xor(hi ? W[5] : W[7], 32);
      uint4 u0, u1;
      u0.x = hi ? e0 : W[0];
      u0.y = hi ? e1 : W[1];
      u0.z = hi ? W[2] : e0;
      u0.w = hi ? W[3] : e1;
      u1.x = hi ? e2 : W[4];
      u1.y = hi ? e3 : W[5];
      u1.z = hi ? W[6] : e2;
      u1.w = hi ? W[7] : e3;
      bf16x8 pa0 = __builtin_bit_cast(bf16x8, u0);
      bf16x8 pa1 = __builtin_bit_cast(bf16x8, u1);
      // PV: O^T += V^T · P^T ; A = V^T rows (d = dc*32 + ql)
#pragma unroll
      for (int dc = 0; dc < 4; ++dc) {
        acc[dc] = __builtin_amdgcn_mfma_f32_32x32x16_bf16(vf[2 * dc], pa0, acc[dc], 0, 0, 0);
        acc[dc] = __builtin_amdgcn_mfma_f32_32x32x16_bf16(vf[2 * dc + 1], pa1, acc[dc], 0, 0, 0);
      }
    }
    __syncthreads();  // all waves done with Ks[i&1]; drains next-tile stage
  }

  // epilogue: combine the two half-row l partials; write normalized partial O + (m,l).
  float l_tot = l_r + __shfl_xor(l_r, 32);
  unsigned short* Pob = (split == 0) ? Po0 : (split == 1) ? Po1 : (split == 2) ? Po2 : Po3;
  float inv = (l_tot > 0.f) ? (1.f / l_tot) : 0.f;
  unsigned short* obase = Pob + ((((size_t)(b * S_) + qrow)) << 11) + (h << 7) + (hi << 2);
#pragma unroll
  for (int dc = 0; dc < 4; ++dc)
#pragma unroll
    for (int gq = 0; gq < 4; ++gq) {
      ushort4 o;
      o.x = f2bfu(acc[dc][4 * gq + 0] * inv);
      o.y = f2bfu(acc[dc][4 * gq + 1] * inv);
      o.z = f2bfu(acc[dc][4 * gq + 2] * inv);
      o.w = f2bfu(acc[dc][4 * gq + 3] * inv);
      *(ushort4*)(obase + (dc << 5) + (gq << 3)) = o;
    }
  if (hi == 0)
    Ml[(size_t)split * (M_ * NH_) + ((size_t)(b * S_) + qrow) * NH_ + h] = make_float2(m_r, l_tot);
}

// combine: Ob = sum_s w_s*Po_s / sum_s w_s, w_s = l_s * 2^(m_s - m)
__global__ void k_comb(const unsigned short* __restrict__ Po0, const unsigned short* __restrict__ Po1,
                       const unsigned short* __restrict__ Po2, const unsigned short* __restrict__ Po3,
                       const float2* __restrict__ Ml, unsigned short* __restrict__ Ob) {
  int idx = blockIdx.x * 256 + threadIdx.x;   // 1,048,576 threads, 8 elems each
  int c = idx >> 4;                           // 128-elem chunk = (b*S+s)*16 + h
  float2 a0 = Ml[c], a1 = Ml[c + M_ * NH_], a2 = Ml[c + 2 * M_ * NH_], a3 = Ml[c + 3 * M_ * NH_];
  float m = fmaxf(fmaxf(a0.x, a1.x), fmaxf(a2.x, a3.x));
  float w0 = a0.y * exp2f(a0.x - m);
  float w1 = a1.y * exp2f(a1.x - m);
  float w2 = a2.y * exp2f(a2.x - m);
  float w3 = a3.y * exp2f(a3.x - m);
  float inv = 1.f / (w0 + w1 + w2 + w3);
  w0 *= inv; w1 *= inv; w2 *= inv; w3 *= inv;
  size_t e = (size_t)idx << 3;
  uint4 v0 = *(const uint4*)(Po0 + e);
  uint4 v1 = *(const uint4*)(Po1 + e);
  uint4 v2 = *(const uint4*)(Po2 + e);
  uint4 v3 = *(const uint4*)(Po3 + e);
  uint4 o;
  o.x = pack2bf(w0 * bflo(v0.x) + w1 * bflo(v1.x) + w2 * bflo(v2.x) + w3 * bflo(v3.x),
                w0 * bfhi(v0.x) + w1 * bfhi(v1.x) + w2 * bfhi(v2.x) + w3 * bfhi(v3.x));
  o.y = pack2bf(w0 * bflo(v0.y) + w1 * bflo(v1.y) + w2 * bflo(v2.y) + w3 * bflo(v3.y),
                w0 * bfhi(v0.y) + w1 * bfhi(v1.y) + w2 * bfhi(v2.y) + w3 * bfhi(v3.y));
  o.z = pack2bf(w0 * bflo(v0.z) + w1 * bflo(v1.z) + w2 * bflo(v2.z) + w3 * bflo(v3.z),
                w0 * bfhi(v0.z) + w1 * bfhi(v1.z) + w2 * bfhi(v2.z) + w3 * bfhi(v3.z));
  o.w = pack2bf(w0 * bflo(v0.w) + w1 * bflo(v1.w) + w2 * bflo(v2.w) + w3 * bflo(v3.w),
                w0 * bfhi(v0.w) + w1 * bfhi(v1.w) + w2 * bfhi(v2.w) + w3 * bfhi(v3.w));
  *(uint4*)(Ob + e) = o;
}

// ---------------- launch ----------------

extern "C" void kernel_launch(void* const* d_in, const int* in_sizes, int n_in,
                              void* d_out, int out_size, void* d_ws, size_t ws_size,
                              hipStream_t stream) {
  const float* X  = (const float*)d_in[0];
  // d_in[1] = causal mask (structure known; ignored)
  const float* Wq = (const float*)d_in[2];
  const float* bq = (const float*)d_in[3];
  const float* Wk = (const float*)d_in[4];
  const float* bk = (const float*)d_in[5];
  const float* Wv = (const float*)d_in[6];
  const float* bv = (const float*)d_in[7];
  const float* Wo = (const float*)d_in[8];
  const float* bo = (const float*)d_in[9];
  float* out = (float*)d_out;

  char* ws = (char*)d_ws;
  unsigned short* Xb  = (unsigned short*)(ws);                  // 16,777,216 B
  unsigned short* Wt  = (unsigned short*)(ws + 16777216);       // 12,582,912
  unsigned short* Wot = (unsigned short*)(ws + 29360128);       //  8,388,608
  float* Bqkv         = (float*)(ws + 37748736);                //     12,288
  float* cosT         = (float*)(ws + 37761024);                //    524,288
  float* sinT         = (float*)(ws + 38285312);                //    524,288
  unsigned short* Cqkvb = (unsigned short*)(ws + 38809600);     // 25,165,824 (bf16 QKV)
  unsigned short* Qr  = (unsigned short*)(ws + 89141248);       // 16,777,216
  unsigned short* Kr  = (unsigned short*)(ws + 105918464);      //  4,194,304
  unsigned short* Vtb = (unsigned short*)(ws + 110112768);      //  4,194,304
  unsigned short* Ob  = (unsigned short*)(ws + 114307072);      // 16,777,216
  // split-KV partials overlaid on dead regions (after GEMM1 + rope/vt):
  unsigned short* Po0 = (unsigned short*)(ws);                            // Xb region, 16MB
  unsigned short* Po1 = (unsigned short*)(ws + 38809600);                 // Cqkv+0
  unsigned short* Po2 = (unsigned short*)(ws + 38809600 + 16777216);      // Cqkv+16M
  unsigned short* Po3 = (unsigned short*)(ws + 38809600 + 33554432);      // Cqkv+32M
  float2* Ml          = (float2*)(ws + 16777216);                         // Wt region, 2MB
  // total ~131 MB

  k_prep<<<8716, 256, 0, stream>>>(X, Xb, bq, bk, bv, Bqkv, cosT, sinT);
  k_tcvtall<<<10240, 256, 0, stream>>>(Wq, Wk, Wv, Wo, Wt, Wot);

  k_gemm<true><<<(M_ / 128) * (NQKV_ / 128), 256, 0, stream>>>(Xb, Wt, Bqkv, Cqkvb, M_, NQKV_, HID_);

  k_rope<<<20992, 256, 0, stream>>>(Cqkvb, cosT, sinT, Qr, Kr, Vtb);

  k_attn<<<B_ * NH_ * (S_ / 128) * NSPLIT, 256, 0, stream>>>(Qr, Kr, Vtb, Po0, Po1, Po2, Po3, Ml);
  k_comb<<<M_ * HID_ / 8 / 256, 256, 0, stream>>>(Po0, Po1, Po2, Po3, Ml, Ob);

  k_gemm<false><<<(M_ / 128) * (HID_ / 128), 256, 0, stream>>>(Ob, Wot, bo, out, M_, HID_, NH_ * HD_);
}

// Round 14
// 232.670 us; speedup vs baseline: 1.3197x; 1.0196x over previous
//
#include <hip/hip_runtime.h>
#include <hip/hip_bf16.h>

#define B_ 2
#define S_ 2048
#define HID_ 2048
#define NH_ 16
#define HD_ 128
#define NKV_ 4
#define M_ (B_*S_)          // 4096
#define NQKV_ 3072          // 2048 Q + 512 K + 512 V
// 1/sqrt(128) * log2(e): QK^T scores land in log2 domain -> exp2f softmax
#define QSCALE2 0.12752464484148957f
#define DEFER_THR 11.5425f  // 8 * log2(e)
#define NSPLIT 4

typedef __bf16 bf16x8 __attribute__((ext_vector_type(8)));
typedef float f32x4 __attribute__((ext_vector_type(4)));
typedef float f32x16 __attribute__((ext_vector_type(16)));

typedef __attribute__((address_space(1))) const unsigned int gas_uint;
typedef __attribute__((address_space(3))) unsigned int las_uint;

__device__ __forceinline__ unsigned short f2bfu(float x) {
  __hip_bfloat16 h = __float2bfloat16(x);
  return __builtin_bit_cast(unsigned short, h);
}

__device__ __forceinline__ unsigned int pack2bf(float lo, float hi) {
  return (unsigned int)f2bfu(lo) | ((unsigned int)f2bfu(hi) << 16);
}

__device__ __forceinline__ float bflo(unsigned int u) {
  return __builtin_bit_cast(float, u << 16);
}
__device__ __forceinline__ float bfhi(unsigned int u) {
  return __builtin_bit_cast(float, u & 0xffff0000u);
}
__device__ __forceinline__ float bf2f(unsigned short u) {
  return __builtin_bit_cast(float, (unsigned int)u << 16);
}

__device__ __forceinline__ void gload_lds16(const void* g, void* l) {
  __builtin_amdgcn_global_load_lds((gas_uint*)g, (las_uint*)l, 16, 0, 0);
}

// ---------------- merged prep kernels ----------------

// regions: [0,8192) X f32->bf16 cvt ; [8192,8204) bias concat ; [8204,8716) rope table
__global__ void k_prep(const float* __restrict__ X, unsigned short* __restrict__ Xb,
                       const float* __restrict__ bq, const float* __restrict__ bk,
                       const float* __restrict__ bv, float* __restrict__ Bqkv,
                       float* __restrict__ cosT, float* __restrict__ sinT) {
  int blk = blockIdx.x;
  if (blk < 8192) {
    int i = blk * 256 + threadIdx.x;           // 2,097,152 float4s
    float4 v = ((const float4*)X)[i];
    ushort4 o;
    o.x = f2bfu(v.x); o.y = f2bfu(v.y); o.z = f2bfu(v.z); o.w = f2bfu(v.w);
    ((ushort4*)Xb)[i] = o;
  } else if (blk < 8204) {
    int i = (blk - 8192) * 256 + threadIdx.x;  // 3072
    float v = (i < 2048) ? bq[i] : (i < 2560 ? bk[i - 2048] : bv[i - 2560]);
    Bqkv[i] = v;
  } else {
    int idx = (blk - 8204) * 256 + threadIdx.x;  // S*64
    int s = idx >> 6, i = idx & 63;
    float invf = expf(-(float)i * (9.210340371976184f / 64.f));  // 10000^(-i/64)
    float ang = (float)s * invf;
    cosT[idx] = cosf(ang);
    sinT[idx] = sinf(ang);
  }
}

// dst[C][R] = bf16(src[R][C]) -- 32x32 LDS transpose; flat tile decode over 4 weights
__global__ void k_tcvtall(const float* __restrict__ Wq, const float* __restrict__ Wk,
                          const float* __restrict__ Wv, const float* __restrict__ Wo,
                          unsigned short* __restrict__ Wt, unsigned short* __restrict__ Wot) {
  __shared__ float t[32][33];
  int blk = blockIdx.x;   // 10240 tiles
  const float* src;
  unsigned short* dst;
  int R, C, bx, by;
  if (blk < 4096)      { src = Wq; dst = Wt;              R = 2048; C = 2048; int i = blk;        bx = i & 63; by = i >> 6; }
  else if (blk < 5120) { src = Wk; dst = Wt + 2048*2048;  R = 2048; C = 512;  int i = blk - 4096; bx = i & 15; by = i >> 4; }
  else if (blk < 6144) { src = Wv; dst = Wt + 2560*2048;  R = 2048; C = 512;  int i = blk - 5120; bx = i & 15; by = i >> 4; }
  else                 { src = Wo; dst = Wot;             R = 2048; C = 2048; int i = blk - 6144; bx = i & 63; by = i >> 6; }
  int bc = bx * 32, br = by * 32;
  int tx = threadIdx.x & 31, ty = threadIdx.x >> 5;
  for (int i = ty; i < 32; i += 8)
    t[i][tx] = src[(size_t)(br + i) * C + bc + tx];
  __syncthreads();
  for (int i = ty; i < 32; i += 8)
    dst[(size_t)(bc + i) * R + br + tx] = f2bfu(t[tx][i]);
}

// V transpose only: Cqkv(bf16)[...][2560+kv*128+d] -> Vt[B][NKV][HD][S]
__global__ void k_vt(const unsigned short* __restrict__ Cq, unsigned short* __restrict__ Vt) {
  __shared__ unsigned short t[32][136];
  int bx = blockIdx.x;                 // 512
  int st = bx & 63, kv = (bx >> 6) & 3, b = bx >> 8;
  int s0 = st * 32;
  int tid = threadIdx.x;
  for (int j = 0; j < 16; ++j) {
    int idx = j * 256 + tid;           // 4096 = 32*128
    int si = idx >> 7, d = idx & 127;
    t[si][d] = Cq[(size_t)(b * S_ + s0 + si) * NQKV_ + 2560 + kv * HD_ + d];
  }
  __syncthreads();
  for (int j = 0; j < 16; ++j) {
    int idx = j * 256 + tid;
    int d = idx >> 5, si = idx & 31;
    Vt[((size_t)(b * NKV_ + kv) * HD_ + d) * S_ + s0 + si] = t[si][d];
  }
}

// ---------------- GEMM: C[M][N] = A[M][K] @ Bt[N][K]^T + bias ----------------
// m97 structure (replay-proven): 128x128 tile, BK=64, global_load_lds w=16,
// XOR-swizzled LDS (T2, rule #21). Wave mapping: 32 rows x 128 cols (acc[2][8])
// so RoPE pairs (c, c+64) are in-lane. MODE 0: f32 out + bias (GEMM2).
// MODE 1: fused bias+RoPE epilogue (GEMM1): bn<16 -> Qr (scaled), 16..19 -> Kr,
// >=20 -> bf16 V region of Cqkvb (k_vt transposes after).

template <int MODE>
__global__ __launch_bounds__(256, 2)
void k_gemm(const unsigned short* __restrict__ A, const unsigned short* __restrict__ Bt,
            const float* __restrict__ bias, void* __restrict__ Cv,
            int Md, int Nd, int Kd,
            const float* __restrict__ cosT, const float* __restrict__ sinT,
            unsigned short* __restrict__ Qr, unsigned short* __restrict__ Kr) {
  __shared__ __align__(16) unsigned short As[128 * 64];
  __shared__ __align__(16) unsigned short Bs[128 * 64];
  int nt = Nd >> 7;
  int nwg = (Md >> 7) * nt;
  int bid = blockIdx.x;
  int wg = bid;
  if ((nwg & 7) == 0) { int cpx = nwg >> 3; wg = (bid & 7) * cpx + (bid >> 3); }
  int bm = wg / nt, bn = wg - bm * nt;
  int tid = threadIdx.x;
  int lane = tid & 63, w = tid >> 6;
  int lr = lane & 15, lg = lane >> 4;
  f32x4 acc[2][8] = {};

  const int chunkbase = w << 2;
  const int boff = lane << 4;
  const int nK = Kd >> 6;
  const size_t rowstride = (size_t)Kd * 2;  // bytes per row

  for (int kt = 0; kt < nK; ++kt) {
#pragma unroll
    for (int i = 0; i < 4; ++i) {
      int off = ((chunkbase + i) << 10) + boff;  // linear byte offset in 16KB tile
      int row = off >> 7;
      int colb = off & 127;
      int scolb = colb ^ ((row & 7) << 4);       // pre-swizzled global source (rule #21)
      const char* ga = (const char*)A + (size_t)(bm * 128 + row) * rowstride + (kt << 7) + scolb;
      const char* gb = (const char*)Bt + (size_t)(bn * 128 + row) * rowstride + (kt << 7) + scolb;
      gload_lds16(ga, (char*)As + ((chunkbase + i) << 10));
      gload_lds16(gb, (char*)Bs + ((chunkbase + i) << 10));
    }
    __syncthreads();
#pragma unroll
    for (int kk = 0; kk < 2; ++kk) {
      bf16x8 a[2], b[8];
      int kb = ((kk << 5) + (lg << 3)) << 1;
#pragma unroll
      for (int mi = 0; mi < 2; ++mi) {
        int row = (w << 5) + (mi << 4) + lr;
        a[mi] = *(const bf16x8*)((const char*)As + (row << 7) + (kb ^ ((row & 7) << 4)));
      }
#pragma unroll
      for (int ni = 0; ni < 8; ++ni) {
        int row = (ni << 4) + lr;
        b[ni] = *(const bf16x8*)((const char*)Bs + (row << 7) + (kb ^ ((row & 7) << 4)));
      }
#pragma unroll
      for (int mi = 0; mi < 2; ++mi)
#pragma unroll
        for (int ni = 0; ni < 8; ++ni)
          acc[mi][ni] = __builtin_amdgcn_mfma_f32_16x16x32_bf16(a[mi], b[ni], acc[mi][ni], 0, 0, 0);
    }
    __syncthreads();
  }

  // C/D layout: col = lane&15, row = (lane>>4)*4 + reg (m89-verified)
  if (MODE == 0 || bn >= 20) {
    // plain epilogue: bias add; f32 (MODE 0) or bf16 V-region (MODE 1)
#pragma unroll
    for (int mi = 0; mi < 2; ++mi) {
      int r0 = bm * 128 + (w << 5) + (mi << 4) + (lg << 2);
#pragma unroll
      for (int ni = 0; ni < 8; ++ni) {
        int col = bn * 128 + (ni << 4) + lr;
        float bz = bias[col];
#pragma unroll
        for (int r = 0; r < 4; ++r) {
          float v = acc[mi][ni][r] + bz;
          if (MODE == 1)
            ((unsigned short*)Cv)[(size_t)(r0 + r) * Nd + col] = f2bfu(v);
          else
            ((float*)Cv)[(size_t)(r0 + r) * Nd + col] = v;
        }
      }
    }
  } else {
    // fused bias + RoPE epilogue (block-uniform branch; pairs (c, c+64) in-lane)
    bool isQ = (bn < 16);
    int hh = isQ ? bn : bn - 16;
#pragma unroll
    for (int mi = 0; mi < 2; ++mi) {
#pragma unroll
      for (int r = 0; r < 4; ++r) {
        int m = bm * 128 + (w << 5) + (mi << 4) + (lg << 2) + r;
        int s = m & (S_ - 1), bb = m >> 11;
        size_t qbase = ((size_t)(bb * NH_ + hh) * S_ + s) * HD_;
        size_t kbase = ((size_t)(bb * NKV_ + hh) * S_ + s) * HD_;
#pragma unroll
        for (int ni = 0; ni < 4; ++ni) {
          int c = (ni << 4) + lr;        // 0..63
          float v1 = acc[mi][ni][r]     + bias[bn * 128 + c];
          float v2 = acc[mi][ni + 4][r] + bias[bn * 128 + c + 64];
          float cs = cosT[(s << 6) + c], sn = sinT[(s << 6) + c];
          float o1 = v1 * cs - v2 * sn;
          float o2 = v1 * sn + v2 * cs;
          if (isQ) {
            Qr[qbase + c]      = f2bfu(o1 * QSCALE2);
            Qr[qbase + c + 64] = f2bfu(o2 * QSCALE2);
          } else {
            Kr[kbase + c]      = f2bfu(o1);
            Kr[kbase + c + 64] = f2bfu(o2);
          }
        }
      }
    }
  }
}

// ---------------- flash attention v8 (replay-proven 115us kernel, unchanged) ----------------
// 4 warps x 32 q-rows, 4-way split-KV, KV64 double-buffered swizzled K LDS,
// swapped-operand 32x32 MFMA, lane-local exp2 softmax, partial-l, 4-shuffle exchange.

__global__ __launch_bounds__(256, 2)
void k_attn(const unsigned short* __restrict__ Qr, const unsigned short* __restrict__ Kr,
            const unsigned short* __restrict__ Vt,
            unsigned short* __restrict__ Po0, unsigned short* __restrict__ Po1,
            unsigned short* __restrict__ Po2, unsigned short* __restrict__ Po3,
            float2* __restrict__ Ml) {
  __shared__ __align__(16) unsigned short Ks[2][64 * 128];
  int bid = blockIdx.x;
  int g = bid & 7;                        // (b,kvh) group -> XCD via round-robin dispatch
  int b = g >> 2, kvh = g & 3;
  int r = bid >> 3;                       // 0..255
  int split = r & 3;
  int r2 = r >> 2;                        // 0..63
  int hg = r2 >> 4;                       // q-head within group 0..3
  int qt = 15 - (r2 & 15);                // long blocks first
  int h = (kvh << 2) + hg;
  int tid = threadIdx.x, lane = tid & 63, w = tid >> 6;
  int ql = lane & 31, hi = lane >> 5;
  int q0 = (qt << 7) + (w << 5);          // warp's first q row
  int qrow = q0 + ql;                     // this lane's q row

  const unsigned short* Qp = Qr + (((size_t)(b * NH_ + h) * S_) << 7);
  const unsigned short* Kp = Kr + (((size_t)(b * NKV_ + kvh) * S_) << 7);
  const unsigned short* Vp = Vt + (((size_t)(b * NKV_ + kvh) * HD_) << 11);

  // Q fragments: qa[c] = Q[qrow][c*16 + hi*8 .. +8]  (B-operand of swapped QK^T)
  bf16x8 qa[8];
#pragma unroll
  for (int c = 0; c < 8; ++c)
    qa[c] = *(const bf16x8*)(Qp + (((size_t)qrow) << 7) + (c << 4) + (hi << 3));

  f32x16 acc[4] = {};                     // acc[dc][r] = O^T[d = dc*32 + crow(r,hi)][qrow]
  float m_r = -1e30f, l_r = 0.f;          // l_r = partial (this half's 16 kv)

  const int T = (qt + 1) << 1;            // total KV64 tiles for this q-tile
  const int nit = (T - split + 3) >> 2;   // tiles for this split: t = split + 4*i

#define STAGE_K(bsel, t)                                                        \
  {                                                                             \
    const char* kbase = (const char*)Kp + ((size_t)(t) << 14);                  \
    _Pragma("unroll")                                                           \
    for (int i_ = 0; i_ < 4; ++i_) {                                            \
      int woff_ = (i_ << 12) + (w << 10);                                       \
      int off_ = woff_ + (lane << 4);                                           \
      int row_ = off_ >> 8;                                                     \
      int colb_ = off_ & 255;                                                   \
      int scolb_ = colb_ ^ ((row_ & 15) << 4);                                  \
      gload_lds16(kbase + ((size_t)row_ << 8) + scolb_,                         \
                  (char*)Ks[bsel] + woff_);                                     \
    }                                                                           \
  }

  STAGE_K(0, split);
  __syncthreads();

  for (int i = 0; i < nit; ++i) {
    int t = split + (i << 2);
    if (i + 1 < nit) STAGE_K((i + 1) & 1, t + 4);   // overlaps with compute below
    const char* Kb = (const char*)Ks[i & 1];

#pragma unroll
    for (int sub = 0; sub < 2; ++sub) {
      int kvbase = (t << 6) + (sub << 5);
      if (kvbase > q0 + 31) continue;     // fully masked for this warp (warp-uniform)

      // QK^T: S^T[kv][q], A = K rows (kv = sub*32 + ql), B = Q^T (from qa)
      f32x16 st = {};
      int krow = (sub << 5) + ql;
      int sw = (krow & 15) << 4;
#pragma unroll
      for (int c = 0; c < 8; ++c) {
        int cb = (c << 5) + (hi << 4);    // byte col within 256B row
        bf16x8 kf = *(const bf16x8*)(Kb + (krow << 8) + (cb ^ sw));
        st = __builtin_amdgcn_mfma_f32_32x32x16_bf16(kf, qa[c], st, 0, 0, 0);
      }
      // V loads issued early (VMEM latency hides under softmax)
      bf16x8 vf[8];
#pragma unroll
      for (int dc = 0; dc < 4; ++dc) {
        const unsigned short* vrow = Vp + (((size_t)((dc << 5) + ql)) << 11) + kvbase + (hi << 3);
        vf[2 * dc]     = *(const bf16x8*)(vrow);
        vf[2 * dc + 1] = *(const bf16x8*)(vrow + 16);
      }
      // causal mask on diagonal sub: kv = kvbase + (r&3) + 8*(r>>2) + 4*hi
      if (kvbase + 31 > q0) {
#pragma unroll
        for (int rr = 0; rr < 16; ++rr) {
          int kv = kvbase + (rr & 3) + ((rr >> 2) << 3) + (hi << 2);
          if (kv > qrow) st[rr] = -1e30f;
        }
      }
      // lane-local online softmax in log2 domain (partner lane^32 has other 16 kv)
      float pmax = st[0];
#pragma unroll
      for (int rr = 1; rr < 16; ++rr) pmax = fmaxf(pmax, st[rr]);
      pmax = fmaxf(pmax, __shfl_xor(pmax, 32));
      if (!__all(pmax <= m_r + DEFER_THR)) {    // defer-max (T13)
        float mn = fmaxf(m_r, pmax);
        float al = exp2f(m_r - mn);
        m_r = mn;
        l_r *= al;
#pragma unroll
        for (int dc = 0; dc < 4; ++dc) acc[dc] = acc[dc] * al;
      }
      float p[16];
      float ps = 0.f;
#pragma unroll
      for (int rr = 0; rr < 16; ++rr) { p[rr] = exp2f(st[rr] - m_r); ps += p[rr]; }
      l_r += ps;                                  // partial; combined at epilogue
      // pack P -> bf16 words; exchange only the 4 partner words each lane uses.
      unsigned int W[8];
#pragma unroll
      for (int i2 = 0; i2 < 8; ++i2) W[i2] = pack2bf(p[2 * i2], p[2 * i2 + 1]);
      unsigned int e0 = __shfl_xor(hi ? W[0] : W[2], 32);
      unsigned int e1 = __shfl_xor(hi ? W[1] : W[3], 32);
      unsigned int e2 = __shfl_xor(hi ? W[4] : W[6], 32);
      unsigned int e3 = __shfl_xor(hi ? W[5] : W[7], 32);
      uint4 u0, u1;
      u0.x = hi ? e0 : W[0];
      u0.y = hi ? e1 : W[1];
      u0.z = hi ? W[2] : e0;
      u0.w = hi ? W[3] : e1;
      u1.x = hi ? e2 : W[4];
      u1.y = hi ? e3 : W[5];
      u1.z = hi ? W[6] : e2;
      u1.w = hi ? W[7] : e3;
      bf16x8 pa0 = __builtin_bit_cast(bf16x8, u0);
      bf16x8 pa1 = __builtin_bit_cast(bf16x8, u1);
      // PV: O^T += V^T · P^T ; A = V^T rows (d = dc*32 + ql)
#pragma unroll
      for (int dc = 0; dc < 4; ++dc) {
        acc[dc] = __builtin_amdgcn_mfma_f32_32x32x16_bf16(vf[2 * dc], pa0, acc[dc], 0, 0, 0);
        acc[dc] = __builtin_amdgcn_mfma_f32_32x32x16_bf16(vf[2 * dc + 1], pa1, acc[dc], 0, 0, 0);
      }
    }
    __syncthreads();  // all waves done with Ks[i&1]; drains next-tile stage
  }

  // epilogue: combine the two half-row l partials; write normalized partial O + (m,l).
  float l_tot = l_r + __shfl_xor(l_r, 32);
  unsigned short* Pob = (split == 0) ? Po0 : (split == 1) ? Po1 : (split == 2) ? Po2 : Po3;
  float inv = (l_tot > 0.f) ? (1.f / l_tot) : 0.f;
  unsigned short* obase = Pob + ((((size_t)(b * S_) + qrow)) << 11) + (h << 7) + (hi << 2);
#pragma unroll
  for (int dc = 0; dc < 4; ++dc)
#pragma unroll
    for (int gq = 0; gq < 4; ++gq) {
      ushort4 o;
      o.x = f2bfu(acc[dc][4 * gq + 0] * inv);
      o.y = f2bfu(acc[dc][4 * gq + 1] * inv);
      o.z = f2bfu(acc[dc][4 * gq + 2] * inv);
      o.w = f2bfu(acc[dc][4 * gq + 3] * inv);
      *(ushort4*)(obase + (dc << 5) + (gq << 3)) = o;
    }
  if (hi == 0)
    Ml[(size_t)split * (M_ * NH_) + ((size_t)(b * S_) + qrow) * NH_ + h] = make_float2(m_r, l_tot);
}

// combine: Ob = sum_s w_s*Po_s / sum_s w_s, w_s = l_s * 2^(m_s - m)
__global__ void k_comb(const unsigned short* __restrict__ Po0, const unsigned short* __restrict__ Po1,
                       const unsigned short* __restrict__ Po2, const unsigned short* __restrict__ Po3,
                       const float2* __restrict__ Ml, unsigned short* __restrict__ Ob) {
  int idx = blockIdx.x * 256 + threadIdx.x;   // 1,048,576 threads, 8 elems each
  int c = idx >> 4;                           // 128-elem chunk = (b*S+s)*16 + h
  float2 a0 = Ml[c], a1 = Ml[c + M_ * NH_], a2 = Ml[c + 2 * M_ * NH_], a3 = Ml[c + 3 * M_ * NH_];
  float m = fmaxf(fmaxf(a0.x, a1.x), fmaxf(a2.x, a3.x));
  float w0 = a0.y * exp2f(a0.x - m);
  float w1 = a1.y * exp2f(a1.x - m);
  float w2 = a2.y * exp2f(a2.x - m);
  float w3 = a3.y * exp2f(a3.x - m);
  float inv = 1.f / (w0 + w1 + w2 + w3);
  w0 *= inv; w1 *= inv; w2 *= inv; w3 *= inv;
  size_t e = (size_t)idx << 3;
  uint4 v0 = *(const uint4*)(Po0 + e);
  uint4 v1 = *(const uint4*)(Po1 + e);
  uint4 v2 = *(const uint4*)(Po2 + e);
  uint4 v3 = *(const uint4*)(Po3 + e);
  uint4 o;
  o.x = pack2bf(w0 * bflo(v0.x) + w1 * bflo(v1.x) + w2 * bflo(v2.x) + w3 * bflo(v3.x),
                w0 * bfhi(v0.x) + w1 * bfhi(v1.x) + w2 * bfhi(v2.x) + w3 * bfhi(v3.x));
  o.y = pack2bf(w0 * bflo(v0.y) + w1 * bflo(v1.y) + w2 * bflo(v2.y) + w3 * bflo(v3.y),
                w0 * bfhi(v0.y) + w1 * bfhi(v1.y) + w2 * bfhi(v2.y) + w3 * bfhi(v3.y));
  o.z = pack2bf(w0 * bflo(v0.z) + w1 * bflo(v1.z) + w2 * bflo(v2.z) + w3 * bflo(v3.z),
                w0 * bfhi(v0.z) + w1 * bfhi(v1.z) + w2 * bfhi(v2.z) + w3 * bfhi(v3.z));
  o.w = pack2bf(w0 * bflo(v0.w) + w1 * bflo(v1.w) + w2 * bflo(v2.w) + w3 * bflo(v3.w),
                w0 * bfhi(v0.w) + w1 * bfhi(v1.w) + w2 * bfhi(v2.w) + w3 * bfhi(v3.w));
  *(uint4*)(Ob + e) = o;
}

// ---------------- launch ----------------

extern "C" void kernel_launch(void* const* d_in, const int* in_sizes, int n_in,
                              void* d_out, int out_size, void* d_ws, size_t ws_size,
                              hipStream_t stream) {
  const float* X  = (const float*)d_in[0];
  // d_in[1] = causal mask (structure known; ignored)
  const float* Wq = (const float*)d_in[2];
  const float* bq = (const float*)d_in[3];
  const float* Wk = (const float*)d_in[4];
  const float* bk = (const float*)d_in[5];
  const float* Wv = (const float*)d_in[6];
  const float* bv = (const float*)d_in[7];
  const float* Wo = (const float*)d_in[8];
  const float* bo = (const float*)d_in[9];
  float* out = (float*)d_out;

  char* ws = (char*)d_ws;
  unsigned short* Xb  = (unsigned short*)(ws);                  // 16,777,216 B
  unsigned short* Wt  = (unsigned short*)(ws + 16777216);       // 12,582,912
  unsigned short* Wot = (unsigned short*)(ws + 29360128);       //  8,388,608
  float* Bqkv         = (float*)(ws + 37748736);                //     12,288
  float* cosT         = (float*)(ws + 37761024);                //    524,288
  float* sinT         = (float*)(ws + 38285312);                //    524,288
  unsigned short* Cqkvb = (unsigned short*)(ws + 38809600);     // 25,165,824 (bf16 QKV; V region live)
  unsigned short* Qr  = (unsigned short*)(ws + 89141248);       // 16,777,216
  unsigned short* Kr  = (unsigned short*)(ws + 105918464);      //  4,194,304
  unsigned short* Vtb = (unsigned short*)(ws + 110112768);      //  4,194,304
  unsigned short* Ob  = (unsigned short*)(ws + 114307072);      // 16,777,216
  // split-KV partials overlaid on dead regions (after GEMM1 + vt):
  unsigned short* Po0 = (unsigned short*)(ws);                            // Xb region, 16MB
  unsigned short* Po1 = (unsigned short*)(ws + 38809600);                 // Cqkv+0
  unsigned short* Po2 = (unsigned short*)(ws + 38809600 + 16777216);      // Cqkv+16M
  unsigned short* Po3 = (unsigned short*)(ws + 38809600 + 33554432);      // Cqkv+32M
  float2* Ml          = (float2*)(ws + 16777216);                         // Wt region, 2MB
  // total ~131 MB

  k_prep<<<8716, 256, 0, stream>>>(X, Xb, bq, bk, bv, Bqkv, cosT, sinT);
  k_tcvtall<<<10240, 256, 0, stream>>>(Wq, Wk, Wv, Wo, Wt, Wot);

  k_gemm<1><<<(M_ / 128) * (NQKV_ / 128), 256, 0, stream>>>(
      Xb, Wt, Bqkv, Cqkvb, M_, NQKV_, HID_, cosT, sinT, Qr, Kr);

  k_vt<<<B_ * NKV_ * (S_ / 32), 256, 0, stream>>>(Cqkvb, Vtb);

  k_attn<<<B_ * NH_ * (S_ / 128) * NSPLIT, 256, 0, stream>>>(Qr, Kr, Vtb, Po0, Po1, Po2, Po3, Ml);
  k_comb<<<M_ * HID_ / 8 / 256, 256, 0, stream>>>(Po0, Po1, Po2, Po3, Ml, Ob);

  k_gemm<0><<<(M_ / 128) * (HID_ / 128), 256, 0, stream>>>(
      Ob, Wot, bo, out, M_, HID_, NH_ * HD_, nullptr, nullptr, nullptr, nullptr);
}